// Round 23
// baseline (482.733 us; speedup 1.0000x reference)
//
#include <hip/hip_runtime.h>
#include <hip/hip_bf16.h>
#include <math.h>
#include <type_traits>

#define TT   1024
#define HH   4096
#define NHH  32
#define DNN  128
#define DRR  64
#define DVV  128
#define QLL  1536
#define KLL  512
#define INHH 32
#define IHDD 128
#define TOPKK 512
#define QKVN 2112

typedef __attribute__((ext_vector_type(8))) short short8;
typedef __attribute__((ext_vector_type(4))) short short4v;
typedef __attribute__((ext_vector_type(4))) float f32x4;

static __device__ __constant__ float kScaling = 0.07216878364870322f;  // (DN+DR)^-0.5
static __device__ __constant__ float kWtsScale = 0.015625f;            // IHD^-.5 * INH^-.5
#define LOG2_10000_OVER_32 0.4152410118609203f

static __device__ __forceinline__ short f2bf(float f) {
  unsigned u = __float_as_uint(f);
  unsigned r = (u + 0x7fffu + ((u >> 16) & 1u)) >> 16;  // RNE
  return (short)r;
}
static __device__ __forceinline__ float bf2f(short s) {
  return __uint_as_float(((unsigned)(unsigned short)s) << 16);
}
// async global->LDS, 16B per lane; lds dest must be wave-uniform base + lane*16
static __device__ __forceinline__ void gl16(const void* g, void* l) {
  __builtin_amdgcn_global_load_lds(
      (const __attribute__((address_space(1))) unsigned int*)g,
      (__attribute__((address_space(3))) unsigned int*)l, 16, 0, 0);
}
// XCD-aware bijective block remap (m204): dispatch slot n -> work id
static __device__ __forceinline__ int xcd_swz(int n, int nwg) {
  const int q = nwg >> 3, r = nwg & 7;
  const int x = n & 7, i = n >> 3;
  return (x < r ? x * (q + 1) : r * (q + 1) + (x - r) * q) + i;
}

// ---------------- rope cos/sin table: [t][i], i in 0..31 ----------------
__global__ void rope_tab(const int* __restrict__ pos,
                         float* __restrict__ ct, float* __restrict__ st) {
  const int t = blockIdx.x, i = threadIdx.x;  // 32 threads
  const float inv = exp2f(-(float)i * LOG2_10000_OVER_32);
  float sn, cs;
  sincosf((float)pos[t] * inv, &sn, &cs);
  ct[t * 32 + i] = cs;
  st[t * 32 + i] = sn;
}

// ---------------- merged idx_qb + q_b GEMM over shared A (qcn), K=1536 ----------------
// grid (80,16): col-tiles 0..31 = idx path (bf16x3, N=4096 -> qih/qil with rope d<64),
// col-tiles 32..79 = q_b path (bf16, N=6144 -> qhb with rope d>=128). 48KB LDS, 3 blk/CU.
__global__ __launch_bounds__(256) void gemm_idxqb(const short* __restrict__ Ah,
                                                  const short* __restrict__ Al,
                                                  const short* __restrict__ Bih,
                                                  const short* __restrict__ Bil,
                                                  const short* __restrict__ Bqb,
                                                  const float* __restrict__ ropeC,
                                                  const float* __restrict__ ropeS,
                                                  short* __restrict__ qih,
                                                  short* __restrict__ qil,
                                                  short* __restrict__ qhb) {
  const int K = QLL;
  __shared__ short AhS[64 * 64], AlS[64 * 64];    // 8 KB + 8 KB
  __shared__ short BhS[128 * 64], BlS[128 * 64];  // 16 KB + 16 KB
  int flat = blockIdx.x + gridDim.x * blockIdx.y;
  flat = xcd_swz(flat, gridDim.x * gridDim.y);
  const int byg = flat % gridDim.y;
  const int bxg = flat / gridDim.y;
  const bool isIdx = (bxg < 32);
  const int tid = threadIdx.x;
  const int lane = tid & 63, wv = tid >> 6;
  const int wc = wv * 32;
  const int bm = byg * 64;
  const int bn = isIdx ? bxg * 128 : (bxg - 32) * 128;
  const int l15 = lane & 15, l4 = lane >> 4;
  const int sx = (l15 & 7) * 8;
  f32x4 acc[4][2];
#pragma unroll
  for (int i = 0; i < 4; ++i)
#pragma unroll
    for (int j = 0; j < 2; ++j) acc[i][j] = f32x4{0.f, 0.f, 0.f, 0.f};

  if (isIdx) {
    // -------- bf16x3 path (idx_qb), BK=64, 4 separate tiles --------
    for (int k0 = 0; k0 < K; k0 += 64) {
      __syncthreads();
#pragma unroll
      for (int i = 0; i < 2; ++i) {            // A hi+lo: 64 rows x 8 chunks each
        const int idx = tid + i * 256;
        const int row = idx >> 3, c8 = (idx & 7) * 8;
        const int cs = c8 ^ ((row & 7) * 8);
        gl16(Ah + (size_t)(bm + row) * K + k0 + cs, &AhS[idx * 8]);
        gl16(Al + (size_t)(bm + row) * K + k0 + cs, &AlS[idx * 8]);
      }
#pragma unroll
      for (int i = 0; i < 4; ++i) {            // B hi+lo: 128 rows x 8 chunks each
        const int idx = tid + i * 256;
        const int row = idx >> 3, c8 = (idx & 7) * 8;
        const int cs = c8 ^ ((row & 7) * 8);
        gl16(Bih + (size_t)(bn + row) * K + k0 + cs, &BhS[idx * 8]);
        gl16(Bil + (size_t)(bn + row) * K + k0 + cs, &BlS[idx * 8]);
      }
      __syncthreads();
      short8 fah[4][2], fal[4][2], fbh[2][2], fbl[2][2];
#pragma unroll
      for (int rt = 0; rt < 4; ++rt) {
        const int row = rt * 16 + l15;
#pragma unroll
        for (int kk = 0; kk < 2; ++kk) {
          const int cc = (kk * 32 + l4 * 8) ^ sx;
          fah[rt][kk] = *(const short8*)&AhS[row * 64 + cc];
          fal[rt][kk] = *(const short8*)&AlS[row * 64 + cc];
        }
      }
#pragma unroll
      for (int ct = 0; ct < 2; ++ct) {
        const int row = wc + ct * 16 + l15;
#pragma unroll
        for (int kk = 0; kk < 2; ++kk) {
          const int cc = (kk * 32 + l4 * 8) ^ sx;
          fbh[ct][kk] = *(const short8*)&BhS[row * 64 + cc];
          fbl[ct][kk] = *(const short8*)&BlS[row * 64 + cc];
        }
      }
#pragma unroll
      for (int kk = 0; kk < 2; ++kk)
#pragma unroll
        for (int ct = 0; ct < 2; ++ct)
#pragma unroll
          for (int rt = 0; rt < 4; ++rt) {
            acc[rt][ct] = __builtin_amdgcn_mfma_f32_16x16x32_bf16(fah[rt][kk], fbh[ct][kk], acc[rt][ct], 0, 0, 0);
            acc[rt][ct] = __builtin_amdgcn_mfma_f32_16x16x32_bf16(fah[rt][kk], fbl[ct][kk], acc[rt][ct], 0, 0, 0);
            acc[rt][ct] = __builtin_amdgcn_mfma_f32_16x16x32_bf16(fal[rt][kk], fbh[ct][kk], acc[rt][ct], 0, 0, 0);
          }
    }
    // epilogue: rope d<64 (table), hi/lo split, write qih/qil [h][row][d]
#pragma unroll
    for (int rt = 0; rt < 4; ++rt)
#pragma unroll
      for (int r = 0; r < 4; ++r) {
        const int row = bm + rt * 16 + l4 * 4 + r;
#pragma unroll
        for (int ct = 0; ct < 2; ++ct) {
          const int col = bn + wc + ct * 16 + l15;
          float v = acc[rt][ct][r];
          const float pv = __shfl_xor(v, 1);   // pair partner (col bit0 == lane bit0)
          const int head = col >> 7, d = col & 127;
          if (d < 64) {
            const int i = d >> 1;
            const float cs = ropeC[row * 32 + i];
            const float sn = ropeS[row * 32 + i];
            v = (col & 1) ? (pv * sn + v * cs) : (v * cs - pv * sn);
          }
          const size_t off = ((size_t)head * 1024 + row) * 128 + d;
          const short hbits = f2bf(v);
          qih[off] = hbits;
          qil[off] = f2bf(v - bf2f(hbits));
        }
      }
  } else {
    // -------- plain bf16 path (q_b), BK=64 --------
    for (int k0 = 0; k0 < K; k0 += 64) {
      __syncthreads();
#pragma unroll
      for (int i = 0; i < 2; ++i) {            // A: 64 rows x 8 chunks
        const int idx = tid + i * 256;
        const int row = idx >> 3, c8 = (idx & 7) * 8;
        const int cs = c8 ^ ((row & 7) * 8);
        gl16(Ah + (size_t)(bm + row) * K + k0 + cs, &AhS[idx * 8]);
      }
#pragma unroll
      for (int i = 0; i < 4; ++i) {            // B: 128 rows x 8 chunks
        const int idx = tid + i * 256;
        const int row = idx >> 3, c8 = (idx & 7) * 8;
        const int cs = c8 ^ ((row & 7) * 8);
        gl16(Bqb + (size_t)(bn + row) * K + k0 + cs, &BhS[idx * 8]);
      }
      __syncthreads();
      short8 fa[4][2], fb[2][2];
#pragma unroll
      for (int rt = 0; rt < 4; ++rt)
#pragma unroll
        for (int kk = 0; kk < 2; ++kk)
          fa[rt][kk] = *(const short8*)(&AhS[(rt * 16 + l15) * 64 + ((kk * 32 + l4 * 8) ^ sx)]);
#pragma unroll
      for (int ct = 0; ct < 2; ++ct)
#pragma unroll
        for (int kk = 0; kk < 2; ++kk)
          fb[ct][kk] = *(const short8*)(&BhS[(wc + ct * 16 + l15) * 64 + ((kk * 32 + l4 * 8) ^ sx)]);
#pragma unroll
      for (int kk = 0; kk < 2; ++kk)
#pragma unroll
        for (int rt = 0; rt < 4; ++rt)
#pragma unroll
          for (int ct = 0; ct < 2; ++ct)
            acc[rt][ct] = __builtin_amdgcn_mfma_f32_16x16x32_bf16(fa[rt][kk], fb[ct][kk], acc[rt][ct], 0, 0, 0);
    }
    // epilogue: rope cols d>=128 of each 192-wide head (table), write qhb[h][row][d]
#pragma unroll
    for (int rt = 0; rt < 4; ++rt)
#pragma unroll
      for (int r = 0; r < 4; ++r) {
        const int row = bm + rt * 16 + l4 * 4 + r;
#pragma unroll
        for (int ct = 0; ct < 2; ++ct) {
          const int col = bn + wc + ct * 16 + l15;
          float v = acc[rt][ct][r];
          const float pv = __shfl_xor(v, 1);   // pair partner (col bit0 == lane bit0)
          const int head = col / 192, d = col - head * 192;
          if (d >= 128) {
            const int i = (d - 128) >> 1;
            const float cs = ropeC[row * 32 + i];
            const float sn = ropeS[row * 32 + i];
            v = (col & 1) ? (pv * sn + v * cs) : (v * cs - pv * sn);
          }
          qhb[((size_t)head * 1024 + row) * 192 + d] = f2bf(v);
        }
      }
  }
}

// ---------------- kv_b GEMM with fused kf/vt repack + kpe broadcast ----------------
// N=8192 = 32 heads x 256 (128 k_nope | 128 v). Even col-tiles -> kfb (+kpe), odd -> vtb.
__global__ __launch_bounds__(256) void gemm_kvb(const short* __restrict__ A,
                                                const short* __restrict__ Bt,
                                                const short* __restrict__ kpe_bf,
                                                short* __restrict__ kfb,
                                                short* __restrict__ vtb) {
  const int K = KLL;
  __shared__ short As[64 * 64];
  __shared__ short Bs[128 * 64];
  __shared__ short tr[128 * 66];
  int flat = blockIdx.x + gridDim.x * blockIdx.y;
  flat = xcd_swz(flat, gridDim.x * gridDim.y);
  const int byg = flat % gridDim.y;
  const int bxg = flat / gridDim.y;
  const int tid = threadIdx.x;
  const int lane = tid & 63, wv = tid >> 6;
  const int wc = wv * 32;
  const int bm = byg * 64, bn = bxg * 128;
  const int l15 = lane & 15, l4 = lane >> 4;
  const int sx = (l15 & 7) * 8;
  f32x4 acc[4][2];
#pragma unroll
  for (int i = 0; i < 4; ++i)
#pragma unroll
    for (int j = 0; j < 2; ++j) acc[i][j] = f32x4{0.f, 0.f, 0.f, 0.f};
  for (int k0 = 0; k0 < K; k0 += 64) {
    __syncthreads();
#pragma unroll
    for (int i = 0; i < 2; ++i) {
      const int idx = tid + i * 256;
      const int row = idx >> 3, c8 = (idx & 7) * 8;
      const int cs = c8 ^ ((row & 7) * 8);
      gl16(A + (size_t)(bm + row) * K + k0 + cs, &As[idx * 8]);
    }
#pragma unroll
    for (int i = 0; i < 4; ++i) {
      const int idx = tid + i * 256;
      const int row = idx >> 3, c8 = (idx & 7) * 8;
      const int cs = c8 ^ ((row & 7) * 8);
      gl16(Bt + (size_t)(bn + row) * K + k0 + cs, &Bs[idx * 8]);
    }
    __syncthreads();
    short8 fa[4][2], fb[2][2];
#pragma unroll
    for (int rt = 0; rt < 4; ++rt)
#pragma unroll
      for (int kk = 0; kk < 2; ++kk)
        fa[rt][kk] = *(const short8*)(&As[(rt * 16 + l15) * 64 + ((kk * 32 + l4 * 8) ^ sx)]);
#pragma unroll
    for (int ct = 0; ct < 2; ++ct)
#pragma unroll
      for (int kk = 0; kk < 2; ++kk)
        fb[ct][kk] = *(const short8*)(&Bs[(wc + ct * 16 + l15) * 64 + ((kk * 32 + l4 * 8) ^ sx)]);
#pragma unroll
    for (int kk = 0; kk < 2; ++kk)
#pragma unroll
      for (int rt = 0; rt < 4; ++rt)
#pragma unroll
        for (int ct = 0; ct < 2; ++ct)
          acc[rt][ct] = __builtin_amdgcn_mfma_f32_16x16x32_bf16(fa[rt][kk], fb[ct][kk], acc[rt][ct], 0, 0, 0);
  }
  const int h = bn >> 8;
  const bool isv = (bn >> 7) & 1;
  if (!isv) {
    // k_nope: kfb[h][row][d], d = wc+ct*16+l15 in 0..127
#pragma unroll
    for (int rt = 0; rt < 4; ++rt)
#pragma unroll
      for (int ct = 0; ct < 2; ++ct)
#pragma unroll
        for (int r = 0; r < 4; ++r) {
          const int row = bm + rt * 16 + l4 * 4 + r;
          const int d = wc + ct * 16 + l15;
          kfb[((size_t)h * 1024 + row) * 192 + d] = f2bf(acc[rt][ct][r]);
        }
    // kpe broadcast: rows bm..bm+63, cols 128..191
#pragma unroll
    for (int i = 0; i < 2; ++i) {
      const int idx = tid + i * 256;         // 512 chunks = 64 rows x 8 chunks
      const int row = idx >> 3, c = idx & 7;
      *(short8*)(kfb + ((size_t)h * 1024 + bm + row) * 192 + 128 + c * 8) =
          *(const short8*)(kpe_bf + (size_t)(bm + row) * 64 + c * 8);
    }
  } else {
    // v: LDS transpose then vtb[h][d][k] coalesced along k
    __syncthreads();
#pragma unroll
    for (int rt = 0; rt < 4; ++rt)
#pragma unroll
      for (int ct = 0; ct < 2; ++ct)
#pragma unroll
        for (int r = 0; r < 4; ++r)
          tr[(wc + ct * 16 + l15) * 66 + rt * 16 + l4 * 4 + r] = f2bf(acc[rt][ct][r]);
    __syncthreads();
    const int d = tid >> 1, half = tid & 1;
    short* dst = vtb + ((size_t)h * 128 + d) * 1024 + bm + half * 32;
#pragma unroll
    for (int c = 0; c < 4; ++c) {
      short8 o;
#pragma unroll
      for (int e = 0; e < 8; ++e) o[e] = tr[d * 66 + half * 32 + c * 8 + e];
      *(short8*)(dst + c * 8) = o;
    }
  }
}

// ---------------- plain bf16 split-K GEMM -> fp32 partials ----------
__global__ __launch_bounds__(256) void gemm1_splitk(const short* __restrict__ A,
                                                    const short* __restrict__ Bt,
                                                    float* __restrict__ part,
                                                    int M, int Np, int K, int kchunk) {
  __shared__ short As[64 * 64];
  __shared__ short Bs[128 * 64];
  int flat = blockIdx.x + gridDim.x * (blockIdx.y + gridDim.y * blockIdx.z);
  flat = xcd_swz(flat, gridDim.x * gridDim.y * gridDim.z);
  const int byg = flat % gridDim.y;
  int tmp = flat / gridDim.y;
  const int bxg = tmp % gridDim.x, bzg = tmp / gridDim.x;
  const int tid = threadIdx.x;
  const int lane = tid & 63, wv = tid >> 6;
  const int wc = wv * 32;
  const int bm = byg * 64, bn = bxg * 128;
  const int kbeg = bzg * kchunk;
  const int l15 = lane & 15, l4 = lane >> 4;
  const int sx = (l15 & 7) * 8;
  f32x4 acc[4][2];
#pragma unroll
  for (int i = 0; i < 4; ++i)
#pragma unroll
    for (int j = 0; j < 2; ++j) acc[i][j] = f32x4{0.f, 0.f, 0.f, 0.f};
  for (int k0 = kbeg; k0 < kbeg + kchunk; k0 += 64) {
    __syncthreads();
#pragma unroll
    for (int i = 0; i < 2; ++i) {
      const int idx = tid + i * 256;
      const int row = idx >> 3, c8 = (idx & 7) * 8;
      const int cs = c8 ^ ((row & 7) * 8);
      gl16(A + (size_t)(bm + row) * K + k0 + cs, &As[idx * 8]);
    }
#pragma unroll
    for (int i = 0; i < 4; ++i) {
      const int idx = tid + i * 256;
      const int row = idx >> 3, c8 = (idx & 7) * 8;
      const int cs = c8 ^ ((row & 7) * 8);
      gl16(Bt + (size_t)(bn + row) * K + k0 + cs, &Bs[idx * 8]);
    }
    __syncthreads();
    short8 fa[4][2], fb[2][2];
#pragma unroll
    for (int rt = 0; rt < 4; ++rt)
#pragma unroll
      for (int kk = 0; kk < 2; ++kk)
        fa[rt][kk] = *(const short8*)(&As[(rt * 16 + l15) * 64 + ((kk * 32 + l4 * 8) ^ sx)]);
#pragma unroll
    for (int ct = 0; ct < 2; ++ct)
#pragma unroll
      for (int kk = 0; kk < 2; ++kk)
        fb[ct][kk] = *(const short8*)(&Bs[(wc + ct * 16 + l15) * 64 + ((kk * 32 + l4 * 8) ^ sx)]);
#pragma unroll
    for (int kk = 0; kk < 2; ++kk)
#pragma unroll
      for (int rt = 0; rt < 4; ++rt)
#pragma unroll
        for (int ct = 0; ct < 2; ++ct)
          acc[rt][ct] = __builtin_amdgcn_mfma_f32_16x16x32_bf16(fa[rt][kk], fb[ct][kk], acc[rt][ct], 0, 0, 0);
  }
  float* dst = part + (size_t)bzg * M * Np;
#pragma unroll
  for (int rt = 0; rt < 4; ++rt)
#pragma unroll
    for (int ct = 0; ct < 2; ++ct)
#pragma unroll
      for (int r = 0; r < 4; ++r)
        dst[(size_t)(bm + rt * 16 + l4 * 4 + r) * Np + bn + wc + ct * 16 + l15] =
            acc[rt][ct][r];
}

// ---------------- deterministic split-K reduce -> fp32 C ----------------
__global__ __launch_bounds__(256) void reduce_splitk(const float* __restrict__ part,
                                                     float* __restrict__ C,
                                                     int M, int Np, int ksplit) {
  const int c = blockIdx.x * 256 + threadIdx.x;
  const int m = blockIdx.y;
  float s = 0.f;
  for (int z = 0; z < ksplit; ++z) s += part[((size_t)z * M + m) * Np + c];
  C[(size_t)m * Np + c] = s;
}

// ---------------- pre-split bf16x3 GEMM, optional split-K ----------------
// BM=64, BK=32, hi/lo fused in [.][64] rows (cols 0-31 hi, 32-63 lo); T2 swizzle.
__global__ __launch_bounds__(256) void gemm3(const short* __restrict__ Ah,
                                             const short* __restrict__ Al,
                                             const short* __restrict__ Bth,
                                             const short* __restrict__ Btl,
                                             float* __restrict__ part,
                                             int M, int Np, int K, int kchunk) {
  __shared__ short AS[64 * 64], BS[128 * 64];
  int flat = blockIdx.x + gridDim.x * (blockIdx.y + gridDim.y * blockIdx.z);
  flat = xcd_swz(flat, gridDim.x * gridDim.y * gridDim.z);
  const int byg = flat % gridDim.y;
  int tmp = flat / gridDim.y;
  const int bxg = tmp % gridDim.x, bzg = tmp / gridDim.x;
  const int tid = threadIdx.x;
  const int lane = tid & 63, wv = tid >> 6;
  const int wc = wv * 32;
  const int l15 = lane & 15, l4 = lane >> 4;
  const int sx = (l15 & 7) * 8;
  const int bm = byg * 64, bn = bxg * 128;
  const int kbeg = bzg * kchunk;
  f32x4 acc[4][2];
#pragma unroll
  for (int i = 0; i < 4; ++i)
#pragma unroll
    for (int j = 0; j < 2; ++j) acc[i][j] = f32x4{0.f, 0.f, 0.f, 0.f};
  for (int k0 = kbeg; k0 < kbeg + kchunk; k0 += 32) {
    __syncthreads();
#pragma unroll
    for (int i = 0; i < 2; ++i) {              // A fused: 64 rows x 8 chunks
      const int idx = tid + i * 256;
      const int row = idx >> 3, c8 = (idx & 7) * 8;
      const int cs = c8 ^ ((row & 7) * 8);     // logical fused col
      const short* srcA = (cs < 32) ? (Ah + (size_t)(bm + row) * K + k0 + cs)
                                    : (Al + (size_t)(bm + row) * K + k0 + (cs - 32));
      gl16(srcA, &AS[idx * 8]);
    }
#pragma unroll
    for (int i = 0; i < 4; ++i) {              // B fused: 128 rows x 8 chunks
      const int idx = tid + i * 256;
      const int row = idx >> 3, c8 = (idx & 7) * 8;
      const int cs = c8 ^ ((row & 7) * 8);
      const short* srcB = (cs < 32) ? (Bth + (size_t)(bn + row) * K + k0 + cs)
                                    : (Btl + (size_t)(bn + row) * K + k0 + (cs - 32));
      gl16(srcB, &BS[idx * 8]);
    }
    __syncthreads();
    short8 fah[4], fal[4], fbh[2], fbl[2];
#pragma unroll
    for (int rt = 0; rt < 4; ++rt) {
      const int row = rt * 16 + l15;
      fah[rt] = *(const short8*)&AS[row * 64 + ((l4 * 8) ^ sx)];
      fal[rt] = *(const short8*)&AS[row * 64 + ((32 + l4 * 8) ^ sx)];
    }
#pragma unroll
    for (int ct = 0; ct < 2; ++ct) {
      const int row = wc + ct * 16 + l15;
      fbh[ct] = *(const short8*)&BS[row * 64 + ((l4 * 8) ^ sx)];
      fbl[ct] = *(const short8*)&BS[row * 64 + ((32 + l4 * 8) ^ sx)];
    }
#pragma unroll
    for (int ct = 0; ct < 2; ++ct)
#pragma unroll
      for (int rt = 0; rt < 4; ++rt) {
        acc[rt][ct] = __builtin_amdgcn_mfma_f32_16x16x32_bf16(fah[rt], fbh[ct], acc[rt][ct], 0, 0, 0);
        acc[rt][ct] = __builtin_amdgcn_mfma_f32_16x16x32_bf16(fah[rt], fbl[ct], acc[rt][ct], 0, 0, 0);
        acc[rt][ct] = __builtin_amdgcn_mfma_f32_16x16x32_bf16(fal[rt], fbh[ct], acc[rt][ct], 0, 0, 0);
      }
  }
  float* dst = part + (size_t)bzg * M * Np;
#pragma unroll
  for (int rt = 0; rt < 4; ++rt)
#pragma unroll
    for (int ct = 0; ct < 2; ++ct)
#pragma unroll
      for (int r = 0; r < 4; ++r)
        dst[(size_t)(bm + rt * 16 + l4 * 4 + r) * Np + bn + wc + ct * 16 + l15] =
            acc[rt][ct][r];
}

// ---------------- fused qkv epilogue: split-K reduce + 2x RMS + kpe rope -> bf16 ------
__global__ __launch_bounds__(256) void qkv_post(const float* __restrict__ qpart,
                                                const float* __restrict__ tpart,
                                                const float* __restrict__ q_ln_w,
                                                const float* __restrict__ kv_ln_w,
                                                const float* __restrict__ ropeC,
                                                const float* __restrict__ ropeS,
                                                short* __restrict__ qcn_bf,
                                                short* __restrict__ qcn_lo,
                                                short* __restrict__ kvn_bf,
                                                short* __restrict__ kpe_bf) {
  const int t = blockIdx.x, tid = threadIdx.x;
  __shared__ float red[4];
  float qv[6];
  float ss = 0.f;
#pragma unroll
  for (int j = 0; j < 6; ++j) {
    const int c = tid + j * 256;
    float s = 0.f;
#pragma unroll
    for (int z = 0; z < 4; ++z) s += qpart[((size_t)z * TT + t) * QLL + c];
    qv[j] = s;
    ss = fmaf(s, s, ss);
  }
#pragma unroll
  for (int o = 32; o > 0; o >>= 1) ss += __shfl_xor(ss, o);
  if ((tid & 63) == 0) red[tid >> 6] = ss;
  __syncthreads();
  const float rq = rsqrtf((red[0] + red[1] + red[2] + red[3]) / (float)QLL + 1e-6f);
  __syncthreads();
#pragma unroll
  for (int j = 0; j < 6; ++j) {
    const int c = tid + j * 256;
    const float v = qv[j] * rq * q_ln_w[c];
    const short h = f2bf(v);
    qcn_bf[(size_t)t * QLL + c] = h;
    qcn_lo[(size_t)t * QLL + c] = f2bf(v - bf2f(h));
  }
  float kv2[2];
  float ss2 = 0.f;
#pragma unroll
  for (int j = 0; j < 2; ++j) {
    const int c = tid + j * 256;
    float s = 0.f;
#pragma unroll
    for (int z = 0; z < 4; ++z) s += tpart[((size_t)z * TT + t) * 640 + c];
    kv2[j] = s;
    ss2 = fmaf(s, s, ss2);
  }
#pragma unroll
  for (int o = 32; o > 0; o >>= 1) ss2 += __shfl_xor(ss2, o);
  if ((tid & 63) == 0) red[tid >> 6] = ss2;
  __syncthreads();
  const float rkv = rsqrtf((red[0] + red[1] + red[2] + red[3]) / (float)KLL + 1e-6f);
#pragma unroll
  for (int j = 0; j < 2; ++j) {
    const int c = tid + j * 256;
    kvn_bf[(size_t)t * KLL + c] = f2bf(kv2[j] * rkv * kv_ln_w[c]);
  }
  if (tid < 32) {
    float x1 = 0.f, x2 = 0.f;
#pragma unroll
    for (int z = 0; z < 4; ++z) {
      x1 += tpart[((size_t)z * TT + t) * 640 + 512 + 2 * tid];
      x2 += tpart[((size_t)z * TT + t) * 640 + 512 + 2 * tid + 1];
    }
    const float cs = ropeC[t * 32 + tid];
    const float sn = ropeS[t * 32 + tid];
    kpe_bf[(size_t)t * 64 + 2 * tid]     = f2bf(x1 * cs - x2 * sn);
    kpe_bf[(size_t)t * 64 + 2 * tid + 1] = f2bf(x1 * sn + x2 * cs);
  }
}

// ---------------- fused ki epilogue: z-sum + LN + RoPE + hi/lo split + wtsb -----------
__global__ __launch_bounds__(256) void ki_prep2(const float* __restrict__ part,
                                                const float* __restrict__ w,
                                                const float* __restrict__ b,
                                                const float* __restrict__ ropeC,
                                                const float* __restrict__ ropeS,
                                                short* __restrict__ kih,
                                                short* __restrict__ kil,
                                                float* __restrict__ wtsb) {
  const int t = blockIdx.x, tid = threadIdx.x;
  __shared__ float red[4], red2[4];
  float s = 0.f;
#pragma unroll
  for (int z = 0; z < 8; ++z) s += part[((size_t)z * TT + t) * 256 + tid];
  if (tid >= 128 && tid < 160) wtsb[(size_t)t * 32 + (tid - 128)] = s;
  const float v = (tid < 128) ? s : 0.f;
  float sm = v;
#pragma unroll
  for (int o = 32; o > 0; o >>= 1) sm += __shfl_xor(sm, o);
  if ((tid & 63) == 0) red[tid >> 6] = sm;
  __syncthreads();
  const float m = (red[0] + red[1]) * (1.f / 128.f);
  const float dv = v - m;
  float sq = (tid < 128) ? dv * dv : 0.f;
#pragma unroll
  for (int o = 32; o > 0; o >>= 1) sq += __shfl_xor(sq, o);
  if ((tid & 63) == 0) red2[tid >> 6] = sq;
  __syncthreads();
  const float var = (red2[0] + red2[1]) * (1.f / 128.f);
  if (tid < 128) {
    float x = dv * rsqrtf(var + 1e-6f) * w[tid] + b[tid];
    if (tid < 64) {
      const float part2 = __shfl_xor(x, 1);
      const int pi = tid >> 1;
      const float cs = ropeC[t * 32 + pi];
      const float sn = ropeS[t * 32 + pi];
      x = (tid & 1) ? (part2 * sn + x * cs) : (x * cs - part2 * sn);
    }
    const short h = f2bf(x);
    kih[(size_t)t * 128 + tid] = h;
    kil[(size_t)t * 128 + tid] = f2bf(x - bf2f(h));
  }
}

// ---------------- f32 -> bf16 hi/lo split (flat) ----------------
__global__ __launch_bounds__(256) void split_cast(const float* __restrict__ in,
                                                  short* __restrict__ hi,
                                                  short* __restrict__ lo, int n4) {
  const int i = blockIdx.x * 256 + threadIdx.x;
  if (i >= n4) return;
  float4 v = *(const float4*)(in + (size_t)i * 4);
  float av[4] = {v.x, v.y, v.z, v.w};
  short4v h, l;
#pragma unroll
  for (int e = 0; e < 4; ++e) {
    h[e] = f2bf(av[e]);
    l[e] = f2bf(av[e] - bf2f(h[e]));
  }
  *(short4v*)(hi + (size_t)i * 4) = h;
  *(short4v*)(lo + (size_t)i * 4) = l;
}

// ---------------- generalized transpose+cast: Bt[n][k] = bf16(B[k][col0+n]) ----------
__global__ __launch_bounds__(256) void transpose_cast_g(const float* __restrict__ B,
                                                        short* __restrict__ Bt,
                                                        int K, int ldB, int col0, int Ncols) {
  __shared__ float tile[64][65];
  const int tid = threadIdx.x;
  const int k0 = blockIdx.y * 64, n0 = blockIdx.x * 64;
  const int nl = tid >> 3, kc = (tid & 7) * 8;
  if (n0 >= Ncols) {
    short8 z = {0, 0, 0, 0, 0, 0, 0, 0};
#pragma unroll
    for (int i = 0; i < 2; ++i) {
      const int n = nl + i * 32;
      *(short8*)(Bt + (size_t)(n0 + n) * K + k0 + kc) = z;
    }
    return;
  }
  const int r = tid >> 4, c4 = (tid & 15) * 4;
#pragma unroll
  for (int i = 0; i < 4; ++i) {
    float4 v = *(const float4*)(B + (size_t)(k0 + r + i * 16) * ldB + col0 + n0 + c4);
    tile[r + i * 16][c4 + 0] = v.x;
    tile[r + i * 16][c4 + 1] = v.y;
    tile[r + i * 16][c4 + 2] = v.z;
    tile[r + i * 16][c4 + 3] = v.w;
  }
  __syncthreads();
#pragma unroll
  for (int i = 0; i < 2; ++i) {
    const int n = nl + i * 32;
    short8 o;
#pragma unroll
    for (int e = 0; e < 8; ++e) o[e] = f2bf(tile[kc + e][n]);
    *(short8*)(Bt + (size_t)(n0 + n) * K + k0 + kc) = o;
  }
}

// ---------------- generalized transpose + hi/lo split cast (partial-tile safe) -------
__global__ __launch_bounds__(256) void transpose_split_cast(const float* __restrict__ B,
                                                            short* __restrict__ Bth,
                                                            short* __restrict__ Btl,
                                                            int K, int ldB, int col0,
                                                            int Ncols) {
  __shared__ float tile[64][65];
  const int tid = threadIdx.x;
  const int k0 = blockIdx.y * 64, n0 = blockIdx.x * 64;
  const int nl = tid >> 3, kc = (tid & 7) * 8;
  if (n0 >= Ncols) {
    short8 z = {0, 0, 0, 0, 0, 0, 0, 0};
#pragma unroll
    for (int i = 0; i < 2; ++i) {
      const int n = nl + i * 32;
      *(short8*)(Bth + (size_t)(n0 + n) * K + k0 + kc) = z;
      *(short8*)(Btl + (size_t)(n0 + n) * K + k0 + kc) = z;
    }
    return;
  }
  const int r = tid >> 4, c4 = (tid & 15) * 4;
#pragma unroll
  for (int i = 0; i < 4; ++i) {
    float4 v = make_float4(0.f, 0.f, 0.f, 0.f);
    if (n0 + c4 < Ncols)
      v = *(const float4*)(B + (size_t)(k0 + r + i * 16) * ldB + col0 + n0 + c4);
    tile[r + i * 16][c4 + 0] = v.x;
    tile[r + i * 16][c4 + 1] = v.y;
    tile[r + i * 16][c4 + 2] = v.z;
    tile[r + i * 16][c4 + 3] = v.w;
  }
  __syncthreads();
#pragma unroll
  for (int i = 0; i < 2; ++i) {
    const int n = nl + i * 32;
    short8 oh, ol;
#pragma unroll
    for (int e = 0; e < 8; ++e) {
      const float x = tile[kc + e][n];
      oh[e] = f2bf(x);
      ol[e] = f2bf(x - bf2f(oh[e]));
    }
    *(short8*)(Bth + (size_t)(n0 + n) * K + k0 + kc) = oh;
    *(short8*)(Btl + (size_t)(n0 + n) * K + k0 + kc) = ol;
  }
}

// ---------------- MFMA indexer logits: triangular grid + XCD swizzle, 8 heads/plane ----
__global__ __launch_bounds__(256) void logits_mfma(const short* __restrict__ qih,
                                                   const short* __restrict__ qil,
                                                   const short* __restrict__ kih_g,
                                                   const short* __restrict__ kil_g,
                                                   const float* __restrict__ wts,
                                                   float* __restrict__ part) {
  const int bid = xcd_swz(blockIdx.x, gridDim.x);
  int bq = (int)((sqrtf(8.f * bid + 1.f) - 1.f) * 0.5f);
  while ((bq + 1) * (bq + 2) / 2 <= bid) ++bq;
  while (bq * (bq + 1) / 2 > bid) --bq;
  const int bk = bid - bq * (bq + 1) / 2;
  const int g = blockIdx.y;  // 0..3 (8 heads each)
  __shared__ short kih[64 * 128], kil[64 * 128];
  __shared__ float swts[64][8];
  const int tid = threadIdx.x;
  const int lane = tid & 63, wv = tid >> 6;
  const int wr = (wv >> 1) * 32, wc = (wv & 1) * 32;
  const int l15 = lane & 15, l4 = lane >> 4;
  const int q0 = bq * 64, k0 = bk * 64;
  {
    const int r0 = tid >> 4;
    const int c8 = (tid & 15) * 8;
#pragma unroll
    for (int i = 0; i < 4; ++i) {
      const int row = r0 + i * 16;
      gl16(kih_g + (size_t)(k0 + row) * 128 + c8, &kih[(tid + i * 256) * 8]);
      gl16(kil_g + (size_t)(k0 + row) * 128 + c8, &kil[(tid + i * 256) * 8]);
    }
  }
#pragma unroll
  for (int i = 0; i < 2; ++i) {
    const int idx = tid + i * 256;
    swts[idx >> 3][idx & 7] = wts[(size_t)(q0 + (idx >> 3)) * 32 + g * 8 + (idx & 7)];
  }
  __syncthreads();
  short8 kbh[2][4], kbl[2][4];
#pragma unroll
  for (int ct = 0; ct < 2; ++ct)
#pragma unroll
    for (int ks = 0; ks < 4; ++ks) {
      kbh[ct][ks] = *(const short8*)&kih[(wc + ct * 16 + l15) * 128 + ks * 32 + l4 * 8];
      kbl[ct][ks] = *(const short8*)&kil[(wc + ct * 16 + l15) * 128 + ks * 32 + l4 * 8];
    }
  f32x4 lacc[2][2];
#pragma unroll
  for (int i = 0; i < 2; ++i)
#pragma unroll
    for (int j = 0; j < 2; ++j) lacc[i][j] = f32x4{0.f, 0.f, 0.f, 0.f};
  for (int hh = 0; hh < 8; ++hh) {
    const int h = g * 8 + hh;
    short8 qah[2][4], qal[2][4];
#pragma unroll
    for (int rt = 0; rt < 2; ++rt)
#pragma unroll
      for (int ks = 0; ks < 4; ++ks) {
        const size_t off = ((size_t)h * 1024 + q0 + wr + rt * 16 + l15) * 128 + ks * 32 + l4 * 8;
        qah[rt][ks] = *(const short8*)(qih + off);
        qal[rt][ks] = *(const short8*)(qil + off);
      }
    f32x4 hacc[2][2];
#pragma unroll
    for (int i = 0; i < 2; ++i)
#pragma unroll
      for (int j = 0; j < 2; ++j) hacc[i][j] = f32x4{0.f, 0.f, 0.f, 0.f};
#pragma unroll
    for (int ks = 0; ks < 4; ++ks)
#pragma unroll
      for (int rt = 0; rt < 2; ++rt)
#pragma unroll
        for (int ct = 0; ct < 2; ++ct) {
          hacc[rt][ct] = __builtin_amdgcn_mfma_f32_16x16x32_bf16(qah[rt][ks], kbh[ct][ks], hacc[rt][ct], 0, 0, 0);
          hacc[rt][ct] = __builtin_amdgcn_mfma_f32_16x16x32_bf16(qah[rt][ks], kbl[ct][ks], hacc[rt][ct], 0, 0, 0);
          hacc[rt][ct] = __builtin_amdgcn_mfma_f32_16x16x32_bf16(qal[rt][ks], kbh[ct][ks], hacc[rt][ct], 0, 0, 0);
        }
#pragma unroll
    for (int rt = 0; rt < 2; ++rt)
#pragma unroll
      for (int ct = 0; ct < 2; ++ct)
#pragma unroll
        for (int r = 0; r < 4; ++r) {
          const int row = wr + rt * 16 + l4 * 4 + r;
          const float w = swts[row][hh] * kWtsScale;
          lacc[rt][ct][r] = fmaf(w, fmaxf(hacc[rt][ct][r], 0.f), lacc[rt][ct][r]);
        }
  }
#pragma unroll
  for (int rt = 0; rt < 2; ++rt)
#pragma unroll
    for (int ct = 0; ct < 2; ++ct)
#pragma unroll
      for (int r = 0; r < 4; ++r)
        part[(size_t)g * TT * TT + (size_t)(q0 + wr + rt * 16 + l4 * 4 + r) * TT +
             (k0 + wc + ct * 16 + l15)] = lacc[rt][ct][r];
}

// ---------------- top-512 -> bitmask: ballot-based, one wave per q-row (4 planes) ------
__global__ __launch_bounds__(256) void topk_mask(const float* __restrict__ part,
                                                 unsigned* __restrict__ maskbuf) {
  const int w = threadIdx.x >> 6;
  const int lane = threadIdx.x & 63;
  const int q = blockIdx.x * 4 + w;
  const size_t NN = (size_t)TT * TT;
  __shared__ unsigned long long bl[4][16];
  unsigned v[16];
#pragma unroll
  for (int j = 0; j < 16; ++j) {
    const int k = j * 64 + lane;
    unsigned uv = 0u;
    if (k <= q) {
      const size_t o = (size_t)q * TT + k;
      const float s = part[o] + part[NN + o] + part[2 * NN + o] + part[3 * NN + o];
      unsigned bb = __float_as_uint(s);
      uv = (bb & 0x80000000u) ? ~bb : (bb | 0x80000000u);
    }
    v[j] = uv;
  }
  if (q + 1 <= TOPKK) {
#pragma unroll
    for (int j = 0; j < 16; ++j) {
      const unsigned long long m = __ballot(j * 64 + lane <= q);
      if (lane == 0) bl[w][j] = m;
    }
  } else {
    unsigned lo = 1u, hi = 0xFFFFFFFFu;
    while (lo < hi) {
      const unsigned mid = lo + ((hi - lo) >> 1) + ((hi - lo) & 1u);
      int c = 0;
#pragma unroll
      for (int j = 0; j < 16; ++j) c += __popcll(__ballot(v[j] >= mid));
      if (c >= TOPKK) lo = mid; else hi = mid - 1u;
    }
    const unsigned ustar = lo;
    int nGreater = 0;
#pragma unroll
    for (int j = 0; j < 16; ++j) nGreater += __popcll(__ballot(v[j] > ustar));
    int need = TOPKK - nGreater;
    const unsigned long long lanemask = lane ? (~0ull >> (64 - lane)) : 0ull;
#pragma unroll
    for (int j = 0; j < 16; ++j) {
      const unsigned long long bg = __ballot(v[j] > ustar);
      const unsigned long long be = __ballot(v[j] == ustar);
      const int ce = __popcll(be);
      const int take = need < ce ? need : ce;
      const int rank = __popcll(be & lanemask);
      const bool selme = ((be >> lane) & 1ull) && (rank < take);
      const unsigned long long m = bg | __ballot(selme);
      if (lane == 0) bl[w][j] = m;
      need -= take;
    }
  }
  __builtin_amdgcn_s_waitcnt(0);
  if (lane < 32)
    maskbuf[(size_t)q * 32 + lane] = (unsigned)(bl[w][lane >> 1] >> ((lane & 1) * 32));
}

// ---------------- masked dense MFMA attention ----------------
__global__ __launch_bounds__(256) void attn_mfma(const short* __restrict__ qh,
                                                 const short* __restrict__ kf,
                                                 const short* __restrict__ vt,
                                                 const unsigned* __restrict__ maskbuf,
                                                 short* __restrict__ ao) {
  const int h = blockIdx.x;
  const int yy = blockIdx.y;
  const int qt = (yy < 8) ? (yy * 2) : (31 - yy * 2);
  const int tid = threadIdx.x;
  const int lane = tid & 63, w = tid >> 6;
  const int l15 = lane & 15, l4 = lane >> 4;
  const int q0 = qt * 64;
  __shared__ short kfs[64 * 200];
  __shared__ short vts[128 * 72];
  __shared__ short ps[4][16][72];
  __shared__ unsigned m32s[64][2];
  short8 qf[6];
#pragma unroll
  for (int ks = 0; ks < 6; ++ks)
    qf[ks] = *(const short8*)(qh + ((size_t)h * 1024 + q0 + w * 16 + l15) * 192 + ks * 32 + l4 * 8);
  f32x4 of[8];
#pragma unroll
  for (int dt = 0; dt < 8; ++dt) of[dt] = f32x4{0.f, 0.f, 0.f, 0.f};
  float m[4], l[4];
#pragma unroll
  for (int r = 0; r < 4; ++r) { m[r] = -INFINITY; l[r] = 0.f; }

  for (int kt = 0; kt <= qt; ++kt) {
    const int k0 = kt * 64;
    __syncthreads();
#pragma unroll
    for (int i = 0; i < 6; ++i) {
      const int idx = tid + i * 256;
      const int row = idx / 24, c = idx - row * 24;
      *(short8*)&kfs[row * 200 + c * 8] =
          *(const short8*)(kf + ((size_t)h * 1024 + k0 + row) * 192 + c * 8);
    }
#pragma unroll
    for (int i = 0; i < 4; ++i) {
      const int idx = tid + i * 256;
      const int row = idx >> 3, c = idx & 7;
      *(short8*)&vts[row * 72 + c * 8] =
          *(const short8*)(vt + ((size_t)h * 128 + row) * 1024 + k0 + c * 8);
    }
    if (tid < 128)
      m32s[tid >> 1][tid & 1] = maskbuf[(size_t)(q0 + (tid >> 1)) * 32 + (k0 >> 5) + (tid & 1)];
    __syncthreads();
    f32x4 sacc[4];
#pragma unroll
    for (int j = 0; j < 4; ++j) sacc[j] = f32x4{0.f, 0.f, 0.f, 0.f};
#pragma unroll
    for (int ks = 0; ks < 6; ++ks)
#pragma unroll
      for (int j = 0; j < 4; ++j) {
        short8 kb = *(const short8*)&kfs[(j * 16 + l15) * 200 + ks * 32 + l4 * 8];
        sacc[j] = __builtin_amdgcn_mfma_f32_16x16x32_bf16(qf[ks], kb, sacc[j], 0, 0, 0);
      }
    float tmax[4] = {-INFINITY, -INFINITY, -INFINITY, -INFINITY};
#pragma unroll
    for (int j = 0; j < 4; ++j)
#pragma unroll
      for (int r = 0; r < 4; ++r) {
        const int kcol = j * 16 + l15;
        const unsigned um = m32s[w * 16 + l4 * 4 + r][kcol >> 5];
        float s = sacc[j][r] * kScaling;
        s = ((um >> (kcol & 31)) & 1u) ? s : -INFINITY;
        sacc[j][r] = s;
        tmax[r] = fmaxf(tmax[r], s);
      }
#pragma unroll
    for (int r = 0; r < 4; ++r) {
      tmax[r] = fmaxf(tmax[r], __shfl_xor(tmax[r], 1));
      tmax[r] = fmaxf(tmax[r], __shfl_xor(tmax[r], 2));
      tmax[r] = fmaxf(tmax[r], __shfl_xor(tmax[r], 4));
      tmax[r] = fmaxf(tmax[r], __shfl_xor(tmax[r], 8));
    }
    float f[4];
#pragma unroll
    for (int r = 0; r < 4; ++r) {
      const float mn = fmaxf(m[r], tmax[r]);
      f[r] = __expf(fmaxf(m[r], -1e30f) - fmaxf(mn, -1e30f));
      m[r] = mn;
      l[r] *= f[r];
    }
    float psum[4] = {0.f, 0.f, 0.f, 0.f};
#pragma unroll
    for (int j = 0; j < 4; ++j)
#pragma unroll
      for (int r = 0; r < 4; ++r) {
        const float p = __expf(sacc[j][r] - fmaxf(m[r], -1e30f));
        psum[r] += p;
        ps[w][l4 * 4 + r][j * 16 + l15] = f2bf(p);
      }
#pragma unroll
    for (int r = 0; r < 4; ++r) {
      psum[r] += __shfl_xor(psum[r], 1);
      psum[r] += __shfl_xor(psum[r], 2);
      psum[r] += __shfl_xor(psum[r], 4);
      psum[r] += __shfl_xor(psum[r], 8);
      l[r] += psum[r];
    }
#pragma unroll
    for (int dt = 0; dt < 8; ++dt)
#pragma unroll
      for (int r = 0; r < 4; ++r) of[dt][r] *= f[r];
    short8 pa0 = *(const short8*)&ps[w][l15][l4 * 8];
    short8 pa1 = *(const short8*)&ps[w][l15][32 + l4 * 8];
#pragma unroll
    for (int dt = 0; dt < 8; ++dt) {
      short8 vb0 = *(const short8*)&vts[(dt * 16 + l15) * 72 + l4 * 8];
      short8 vb1 = *(const short8*)&vts[(dt * 16 + l15) * 72 + 32 + l4 * 8];
      of[dt] = __builtin_amdgcn_mfma_f32_16x16x32_bf16(pa0, vb0, of[dt], 0, 0, 0);
      of[dt] = __builtin_amdgcn_mfma_f32_16x16x32_bf16(pa1, vb1, of[dt], 0, 0, 0);
    }
  }
#pragma unroll
  for (int r = 0; r < 4; ++r) {
    const float invl = 1.f / l[r];
#pragma unroll
    for (int dt = 0; dt < 8; ++dt)
      ao[(size_t)(q0 + w * 16 + l4 * 4 + r) * 4096 + h * 128 + dt * 16 + l15] =
          f2bf(of[dt][r] * invl);
  }
}

// ============================================================================
extern "C" void kernel_launch(void* const* d_in, const int* in_sizes, int n_in,
                              void* d_out, int out_size, void* d_ws, size_t ws_size,
                              hipStream_t stream) {
  const float* hidden     = (const float*)d_in[0];
  const int*   positions  = (const int*)d_in[1];
  const float* w_qkv_a    = (const float*)d_in[2];
  const float* q_a_ln_w   = (const float*)d_in[3];
  const float* w_q_b      = (const float*)d_in[4];
  const float* kv_a_ln_w  = (const float*)d_in[5];
  const float* w_kv_b     = (const float*)d_in[6];
  const float* w_o        = (const float*)d_in[7];
  const float* w_idx_qb   = (const float*)d_in[8];
  const float* w_idx_k    = (const float*)d_in[9];
  const float* idx_k_ln_w = (const float*)d_in[10];
  const float* idx_k_ln_b = (const float*)d_in[11];
  const float* w_idx_w    = (const float*)d_in[12];
  float* out = (float*)d_out;

  float* ws = (float*)d_ws;
  size_t off = 0;
  auto take = [&](size_t n) { float* p = ws + off; off += n; return p; };
  short* qcn_bf  = (short*)take((size_t)TT * QLL / 2);
  short* qcn_lo  = (short*)take((size_t)TT * QLL / 2);
  short* kvn_bf  = (short*)take((size_t)TT * KLL / 2);
  short* kpe_bf  = (short*)take((size_t)TT * 32);
  float* wtsb    = take((size_t)TT * INHH);
  float* rope_ct = take((size_t)TT * 32);
  float* rope_st = take((size_t)TT * 32);
  short* kih_g   = (short*)take((size_t)TT * IHDD / 2);
  short* kil_g   = (short*)take((size_t)TT * IHDD / 2);
  short* qhb     = (short*)take((size_t)NHH * TT * 192 / 2);   // bf16 [h][q][192]
  short* kfb     = (short*)take((size_t)NHH * TT * 192 / 2);   // bf16 [h][k][192]
  short* vtb     = (short*)take((size_t)NHH * 128 * TT / 2);   // bf16 [h][d][k]
  short* qih_h   = (short*)take((size_t)INHH * TT * 128 / 2);
  short* qih_l   = (short*)take((size_t)INHH * TT * 128 / 2);
  float* part4   = take((size_t)4 * TT * TT);
  unsigned* maskbuf = (unsigned*)take((size_t)TT * 32);
  short* hid_h   = (short*)take((size_t)TT * HH / 2);
  short* hid_l   = (short*)take((size_t)TT * HH / 2);
  short* wqkva_h = (short*)take((size_t)QLL * HH / 2);
  short* wqkva_l = (short*)take((size_t)QLL * HH / 2);
  short* wtail_t = (short*)take((size_t)640 * HH / 2);
  short* wsk_h   = (short*)take((size_t)256 * HH / 2);
  short* wsk_l   = (short*)take((size_t)256 * HH / 2);
  short* widxqb_h = (short*)take((size_t)HH * QLL / 2);
  short* widxqb_l = (short*)take((size_t)HH * QLL / 2);
  short* wqb_t   = (short*)take((size_t)6144 * QLL / 2);
  short* wkvb_t  = (short*)take((size_t)8192 * KLL / 2);
  short* ao   = (short*)part4;       // alias: part4[0 .. 2.1M floats), dead after topk
  short* wo_t = hid_h;               // alias: hid dead after qkv gemms
  float* skpart = part4;             // alias: 8*1024*256 = 2.1M floats < part4 (not live yet)
  // qkvpart 4x1024x1536 = 6.29M floats = vtb(2.10M)+qih_h(2.10M)+qih_l(2.10M) floats exactly
  float* qkvpart = (float*)vtb;
  // tailpart 4x1024x640 = 2.62M floats < qhb (3.14M floats) — qhb written later by gemm_idxqb
  float* tailpart = (float*)qhb;
  // w_o split-K partials: 2x1024x4096 = 8.39M floats reusing the qhb..vtb span —
  // qhb/kfb/vtb are dead after attn_mfma; ao lives in part4 and wo_t in hid_h (no overlap).
  float* wopart = (float*)qhb;

  const dim3 blk(256);
  // rope table (only dep: positions)
  rope_tab<<<dim3(TT), 32, 0, stream>>>(positions, rope_ct, rope_st);
  // input/weight splits
  split_cast<<<dim3(TT * HH / 4 / 256), blk, 0, stream>>>(hidden, hid_h, hid_l, TT * HH / 4);
  transpose_split_cast<<<dim3(QLL / 64, HH / 64), blk, 0, stream>>>(w_qkv_a, wqkva_h, wqkva_l, HH, QKVN, 0, QLL);
  transpose_cast_g<<<dim3(640 / 64, HH / 64), blk, 0, stream>>>(w_qkv_a, wtail_t, HH, QKVN, QLL, QKVN - QLL);
  transpose_split_cast<<<dim3(HH / 64, QLL / 64), blk, 0, stream>>>(w_idx_qb, widxqb_h, widxqb_l, QLL, HH, 0, HH);
  transpose_split_cast<<<dim3(2, HH / 64), blk, 0, stream>>>(w_idx_k, wsk_h, wsk_l, HH, 128, 0, 128);
  transpose_split_cast<<<dim3(2, HH / 64), blk, 0, stream>>>(w_idx_w, wsk_h + (size_t)128 * HH,
                                                            wsk_l + (size_t)128 * HH, HH, 32, 0, 32);
  transpose_cast_g<<<dim3(6144 / 64, QLL / 64), blk, 0, stream>>>(w_q_b, wqb_t, QLL, 6144, 0, 6144);
  transpose_cast_g<<<dim3(8192 / 64, KLL / 64), blk, 0, stream>>>(w_kv_b, wkvb_t, KLL, 8192, 0, 8192);
  // skinny projections via bf16x3 MFMA z=8; partials in part4
  gemm3<<<dim3(2, 16, 8), blk, 0, stream>>>(hid_h, hid_l, wsk_h, wsk_l,
                                            skpart, TT, 256, HH, HH / 8);
  ki_prep2<<<dim3(TT), blk, 0, stream>>>(skpart, idx_k_ln_w, idx_k_ln_b, rope_ct, rope_st,
                                         kih_g, kil_g, wtsb);
  // qkv_a q_c: bf16x3 split-K z=4 -> qkvpart (vtb+qih span)
  gemm3<<<dim3(QLL / 128, 16, 4), blk, 0, stream>>>(hid_h, hid_l, wqkva_h, wqkva_l,
                                                    qkvpart, TT, QLL, HH, HH / 4);
  // qkv_a kv/kpe tail: z=4 -> tailpart (qhb span)
  gemm1_splitk<<<dim3(5, 16, 4), blk, 0, stream>>>(hid_h, wtail_t, tailpart, TT, 640, HH, HH / 4);
  // fused epilogue -> qcn hi/lo, kvn, kpe_bf
  qkv_post<<<dim3(TT), blk, 0, stream>>>(qkvpart, tailpart, q_a_ln_w, kv_a_ln_w,
                                         rope_ct, rope_st, qcn_bf, qcn_lo, kvn_bf, kpe_bf);
  // w_o transpose (hid region dead)
  transpose_cast_g<<<dim3(HH / 64, HH / 64), blk, 0, stream>>>(w_o, wo_t, HH, HH, 0, HH);
  // merged idx_qb + q_b GEMM: 80 col-tiles x 16 row-tiles = 1280 blocks
  // (qkvpart/tailpart spans dead after qkv_post; writes qih/qil + qhb)
  gemm_idxqb<<<dim3(80, 16), blk, 0, stream>>>(qcn_bf, qcn_lo, widxqb_h, widxqb_l, wqb_t,
                                               rope_ct, rope_st, qih_h, qih_l, qhb);
  // kv_b with fused repack
  gemm_kvb<<<dim3(64, 16), blk, 0, stream>>>(kvn_bf, wkvb_t, kpe_bf, kfb, vtb);
  // indexer logits (triangular + XCD swizzle, 4 planes)
  logits_mfma<<<dim3(136, 4), blk, 0, stream>>>(qih_h, qih_l, kih_g, kil_g, wtsb, part4);
  // top-512 -> bitmask
  topk_mask<<<dim3(TT / 4), blk, 0, stream>>>(part4, maskbuf);
  // masked dense MFMA attention
  attn_mfma<<<dim3(NHH, 16), blk, 0, stream>>>(qhb, kfb, vtb, maskbuf, ao);
  // output projection: split-K z=2 (1024 blocks = 4/CU) + deterministic reduce
  gemm1_splitk<<<dim3(HH / 128, 16, 2), blk, 0, stream>>>(ao, wo_t, wopart, TT, HH,
                                                          NHH * DVV, NHH * DVV / 2);
  reduce_splitk<<<dim3(HH / 256, TT), blk, 0, stream>>>(wopart, out, TT, HH, 2);
}

// Round 24
// 455.127 us; speedup vs baseline: 1.0607x; 1.0607x over previous
//
#include <hip/hip_runtime.h>
#include <hip/hip_bf16.h>
#include <math.h>
#include <type_traits>

#define TT   1024
#define HH   4096
#define NHH  32
#define DNN  128
#define DRR  64
#define DVV  128
#define QLL  1536
#define KLL  512
#define INHH 32
#define IHDD 128
#define TOPKK 512
#define QKVN 2112

typedef __attribute__((ext_vector_type(8))) short short8;
typedef __attribute__((ext_vector_type(4))) short short4v;
typedef __attribute__((ext_vector_type(4))) float f32x4;

static __device__ __constant__ float kScaling = 0.07216878364870322f;  // (DN+DR)^-0.5
static __device__ __constant__ float kWtsScale = 0.015625f;            // IHD^-.5 * INH^-.5
#define LOG2_10000_OVER_32 0.4152410118609203f

static __device__ __forceinline__ short f2bf(float f) {
  unsigned u = __float_as_uint(f);
  unsigned r = (u + 0x7fffu + ((u >> 16) & 1u)) >> 16;  // RNE
  return (short)r;
}
static __device__ __forceinline__ float bf2f(short s) {
  return __uint_as_float(((unsigned)(unsigned short)s) << 16);
}
// async global->LDS, 16B per lane; lds dest must be wave-uniform base + lane*16
static __device__ __forceinline__ void gl16(const void* g, void* l) {
  __builtin_amdgcn_global_load_lds(
      (const __attribute__((address_space(1))) unsigned int*)g,
      (__attribute__((address_space(3))) unsigned int*)l, 16, 0, 0);
}
// XCD-aware bijective block remap (m204): dispatch slot n -> work id
static __device__ __forceinline__ int xcd_swz(int n, int nwg) {
  const int q = nwg >> 3, r = nwg & 7;
  const int x = n & 7, i = n >> 3;
  return (x < r ? x * (q + 1) : r * (q + 1) + (x - r) * q) + i;
}

// ---------------- rope cos/sin table: [t][i], i in 0..31 ----------------
__global__ void rope_tab(const int* __restrict__ pos,
                         float* __restrict__ ct, float* __restrict__ st) {
  const int t = blockIdx.x, i = threadIdx.x;  // 32 threads
  const float inv = exp2f(-(float)i * LOG2_10000_OVER_32);
  float sn, cs;
  sincosf((float)pos[t] * inv, &sn, &cs);
  ct[t * 32 + i] = cs;
  st[t * 32 + i] = sn;
}

// ---------------- plain bf16 MFMA GEMM: C = A @ Bt^T ----------------
// BM=64, BN=128, BK=64, 4 waves (64x32 each), gl16 + T2 swizzle, m97 2-barrier.
template <typename CT>
__global__ __launch_bounds__(256) void gemm_bf16(const short* __restrict__ A,
                                                 const short* __restrict__ Bt,
                                                 CT* __restrict__ C,
                                                 int M, int N, int K) {
  __shared__ short As[64 * 64];
  __shared__ short Bs[128 * 64];
  int flat = blockIdx.x + gridDim.x * blockIdx.y;
  flat = xcd_swz(flat, gridDim.x * gridDim.y);
  const int byg = flat % gridDim.y;            // M fastest: XCD chunk shares B-panels
  const int bxg = flat / gridDim.y;
  const int tid = threadIdx.x;
  const int lane = tid & 63, wv = tid >> 6;
  const int wc = wv * 32;
  const int bm = byg * 64, bn = bxg * 128;
  const int l15 = lane & 15, l4 = lane >> 4;
  const int sx = (l15 & 7) * 8;                // read-side swizzle (shorts)
  f32x4 acc[4][2];
#pragma unroll
  for (int i = 0; i < 4; ++i)
#pragma unroll
    for (int j = 0; j < 2; ++j) acc[i][j] = f32x4{0.f, 0.f, 0.f, 0.f};
  for (int k0 = 0; k0 < K; k0 += 64) {
    __syncthreads();
#pragma unroll
    for (int i = 0; i < 2; ++i) {              // A: 64 rows x 8 chunks
      const int idx = tid + i * 256;
      const int row = idx >> 3, c8 = (idx & 7) * 8;
      const int cs = c8 ^ ((row & 7) * 8);
      gl16(A + (size_t)(bm + row) * K + k0 + cs, &As[idx * 8]);
    }
#pragma unroll
    for (int i = 0; i < 4; ++i) {              // B: 128 rows x 8 chunks
      const int idx = tid + i * 256;
      const int row = idx >> 3, c8 = (idx & 7) * 8;
      const int cs = c8 ^ ((row & 7) * 8);
      gl16(Bt + (size_t)(bn + row) * K + k0 + cs, &Bs[idx * 8]);
    }
    __syncthreads();
    short8 fa[4][2], fb[2][2];
#pragma unroll
    for (int rt = 0; rt < 4; ++rt)
#pragma unroll
      for (int kk = 0; kk < 2; ++kk)
        fa[rt][kk] = *(const short8*)(&As[(rt * 16 + l15) * 64 + ((kk * 32 + l4 * 8) ^ sx)]);
#pragma unroll
    for (int ct = 0; ct < 2; ++ct)
#pragma unroll
      for (int kk = 0; kk < 2; ++kk)
        fb[ct][kk] = *(const short8*)(&Bs[(wc + ct * 16 + l15) * 64 + ((kk * 32 + l4 * 8) ^ sx)]);
#pragma unroll
    for (int kk = 0; kk < 2; ++kk)
#pragma unroll
      for (int rt = 0; rt < 4; ++rt)
#pragma unroll
        for (int ct = 0; ct < 2; ++ct)
          acc[rt][ct] = __builtin_amdgcn_mfma_f32_16x16x32_bf16(fa[rt][kk], fb[ct][kk], acc[rt][ct], 0, 0, 0);
  }
#pragma unroll
  for (int rt = 0; rt < 4; ++rt)
#pragma unroll
    for (int ct = 0; ct < 2; ++ct)
#pragma unroll
      for (int r = 0; r < 4; ++r) {
        const int row = bm + rt * 16 + l4 * 4 + r;
        const int col = bn + wc + ct * 16 + l15;
        const float v = acc[rt][ct][r];
        if constexpr (std::is_same<CT, float>::value) C[(size_t)row * N + col] = v;
        else C[(size_t)row * N + col] = __float2bfloat16(v);
      }
}

// ---------------- q_b GEMM with fused RoPE (table) + [h][q][192] repack ----------------
__global__ __launch_bounds__(256) void gemm_qb(const short* __restrict__ A,
                                               const short* __restrict__ Bt,
                                               const float* __restrict__ ropeC,
                                               const float* __restrict__ ropeS,
                                               short* __restrict__ qhb) {
  const int M = TT, N = 6144, K = QLL;
  __shared__ short As[64 * 64];
  __shared__ short Bs[128 * 64];
  int flat = blockIdx.x + gridDim.x * blockIdx.y;
  flat = xcd_swz(flat, gridDim.x * gridDim.y);
  const int byg = flat % gridDim.y;
  const int bxg = flat / gridDim.y;
  const int tid = threadIdx.x;
  const int lane = tid & 63, wv = tid >> 6;
  const int wc = wv * 32;
  const int bm = byg * 64, bn = bxg * 128;
  const int l15 = lane & 15, l4 = lane >> 4;
  const int sx = (l15 & 7) * 8;
  f32x4 acc[4][2];
#pragma unroll
  for (int i = 0; i < 4; ++i)
#pragma unroll
    for (int j = 0; j < 2; ++j) acc[i][j] = f32x4{0.f, 0.f, 0.f, 0.f};
  for (int k0 = 0; k0 < K; k0 += 64) {
    __syncthreads();
#pragma unroll
    for (int i = 0; i < 2; ++i) {
      const int idx = tid + i * 256;
      const int row = idx >> 3, c8 = (idx & 7) * 8;
      const int cs = c8 ^ ((row & 7) * 8);
      gl16(A + (size_t)(bm + row) * K + k0 + cs, &As[idx * 8]);
    }
#pragma unroll
    for (int i = 0; i < 4; ++i) {
      const int idx = tid + i * 256;
      const int row = idx >> 3, c8 = (idx & 7) * 8;
      const int cs = c8 ^ ((row & 7) * 8);
      gl16(Bt + (size_t)(bn + row) * K + k0 + cs, &Bs[idx * 8]);
    }
    __syncthreads();
    short8 fa[4][2], fb[2][2];
#pragma unroll
    for (int rt = 0; rt < 4; ++rt)
#pragma unroll
      for (int kk = 0; kk < 2; ++kk)
        fa[rt][kk] = *(const short8*)(&As[(rt * 16 + l15) * 64 + ((kk * 32 + l4 * 8) ^ sx)]);
#pragma unroll
    for (int ct = 0; ct < 2; ++ct)
#pragma unroll
      for (int kk = 0; kk < 2; ++kk)
        fb[ct][kk] = *(const short8*)(&Bs[(wc + ct * 16 + l15) * 64 + ((kk * 32 + l4 * 8) ^ sx)]);
#pragma unroll
    for (int kk = 0; kk < 2; ++kk)
#pragma unroll
      for (int rt = 0; rt < 4; ++rt)
#pragma unroll
        for (int ct = 0; ct < 2; ++ct)
          acc[rt][ct] = __builtin_amdgcn_mfma_f32_16x16x32_bf16(fa[rt][kk], fb[ct][kk], acc[rt][ct], 0, 0, 0);
  }
  // epilogue: rope cols d>=128 of each 192-wide head (table), write qhb[h][row][d]
#pragma unroll
  for (int rt = 0; rt < 4; ++rt)
#pragma unroll
    for (int r = 0; r < 4; ++r) {
      const int row = bm + rt * 16 + l4 * 4 + r;
#pragma unroll
      for (int ct = 0; ct < 2; ++ct) {
        const int col = bn + wc + ct * 16 + l15;
        float v = acc[rt][ct][r];
        const float pv = __shfl_xor(v, 1);     // pair partner (col bit0 == lane bit0)
        const int head = col / 192, d = col - head * 192;
        if (d >= 128) {
          const int i = (d - 128) >> 1;
          const float cs = ropeC[row * 32 + i];
          const float sn = ropeS[row * 32 + i];
          v = (col & 1) ? (pv * sn + v * cs) : (v * cs - pv * sn);
        }
        qhb[((size_t)head * 1024 + row) * 192 + d] = f2bf(v);
      }
    }
}

// ---------------- idx_qb GEMM (bf16x3, BK=64, z=1) with fused RoPE + repack + split ----
// N=4096 = 32 idx-heads x 128. Epilogue: rope d<64, write qih_h/qih_l [h][q][128].
__global__ __launch_bounds__(256) void gemm_idx(const short* __restrict__ Ah,
                                                const short* __restrict__ Al,
                                                const short* __restrict__ Bth,
                                                const short* __restrict__ Btl,
                                                const float* __restrict__ ropeC,
                                                const float* __restrict__ ropeS,
                                                short* __restrict__ qih,
                                                short* __restrict__ qil) {
  const int K = QLL;
  __shared__ short AhS[64 * 64], AlS[64 * 64];    // 8 KB + 8 KB
  __shared__ short BhS[128 * 64], BlS[128 * 64];  // 16 KB + 16 KB
  int flat = blockIdx.x + gridDim.x * blockIdx.y;
  flat = xcd_swz(flat, gridDim.x * gridDim.y);
  const int byg = flat % gridDim.y;
  const int bxg = flat / gridDim.y;
  const int tid = threadIdx.x;
  const int lane = tid & 63, wv = tid >> 6;
  const int wc = wv * 32;
  const int bm = byg * 64, bn = bxg * 128;
  const int l15 = lane & 15, l4 = lane >> 4;
  const int sx = (l15 & 7) * 8;
  f32x4 acc[4][2];
#pragma unroll
  for (int i = 0; i < 4; ++i)
#pragma unroll
    for (int j = 0; j < 2; ++j) acc[i][j] = f32x4{0.f, 0.f, 0.f, 0.f};
  for (int k0 = 0; k0 < K; k0 += 64) {
    __syncthreads();
#pragma unroll
    for (int i = 0; i < 2; ++i) {              // A hi + lo: 64 rows x 8 chunks each
      const int idx = tid + i * 256;
      const int row = idx >> 3, c8 = (idx & 7) * 8;
      const int cs = c8 ^ ((row & 7) * 8);
      gl16(Ah + (size_t)(bm + row) * K + k0 + cs, &AhS[idx * 8]);
      gl16(Al + (size_t)(bm + row) * K + k0 + cs, &AlS[idx * 8]);
    }
#pragma unroll
    for (int i = 0; i < 4; ++i) {              // B hi + lo: 128 rows x 8 chunks each
      const int idx = tid + i * 256;
      const int row = idx >> 3, c8 = (idx & 7) * 8;
      const int cs = c8 ^ ((row & 7) * 8);
      gl16(Bth + (size_t)(bn + row) * K + k0 + cs, &BhS[idx * 8]);
      gl16(Btl + (size_t)(bn + row) * K + k0 + cs, &BlS[idx * 8]);
    }
    __syncthreads();
    short8 fah[4][2], fal[4][2], fbh[2][2], fbl[2][2];
#pragma unroll
    for (int rt = 0; rt < 4; ++rt) {
      const int row = rt * 16 + l15;
#pragma unroll
      for (int kk = 0; kk < 2; ++kk) {
        const int cc = (kk * 32 + l4 * 8) ^ sx;
        fah[rt][kk] = *(const short8*)&AhS[row * 64 + cc];
        fal[rt][kk] = *(const short8*)&AlS[row * 64 + cc];
      }
    }
#pragma unroll
    for (int ct = 0; ct < 2; ++ct) {
      const int row = wc + ct * 16 + l15;
#pragma unroll
      for (int kk = 0; kk < 2; ++kk) {
        const int cc = (kk * 32 + l4 * 8) ^ sx;
        fbh[ct][kk] = *(const short8*)&BhS[row * 64 + cc];
        fbl[ct][kk] = *(const short8*)&BlS[row * 64 + cc];
      }
    }
#pragma unroll
    for (int kk = 0; kk < 2; ++kk)
#pragma unroll
      for (int ct = 0; ct < 2; ++ct)
#pragma unroll
        for (int rt = 0; rt < 4; ++rt) {
          acc[rt][ct] = __builtin_amdgcn_mfma_f32_16x16x32_bf16(fah[rt][kk], fbh[ct][kk], acc[rt][ct], 0, 0, 0);
          acc[rt][ct] = __builtin_amdgcn_mfma_f32_16x16x32_bf16(fah[rt][kk], fbl[ct][kk], acc[rt][ct], 0, 0, 0);
          acc[rt][ct] = __builtin_amdgcn_mfma_f32_16x16x32_bf16(fal[rt][kk], fbh[ct][kk], acc[rt][ct], 0, 0, 0);
        }
  }
  // epilogue: rope d<64 (table), hi/lo split, write qih/qil [h][row][d]
#pragma unroll
  for (int rt = 0; rt < 4; ++rt)
#pragma unroll
    for (int r = 0; r < 4; ++r) {
      const int row = bm + rt * 16 + l4 * 4 + r;
#pragma unroll
      for (int ct = 0; ct < 2; ++ct) {
        const int col = bn + wc + ct * 16 + l15;
        float v = acc[rt][ct][r];
        const float pv = __shfl_xor(v, 1);     // pair partner (col bit0 == lane bit0)
        const int head = col >> 7, d = col & 127;
        if (d < 64) {
          const int i = d >> 1;
          const float cs = ropeC[row * 32 + i];
          const float sn = ropeS[row * 32 + i];
          v = (col & 1) ? (pv * sn + v * cs) : (v * cs - pv * sn);
        }
        const size_t off = ((size_t)head * 1024 + row) * 128 + d;
        const short hbits = f2bf(v);
        qih[off] = hbits;
        qil[off] = f2bf(v - bf2f(hbits));
      }
    }
}

// ---------------- kv_b GEMM with fused kf/vt repack + kpe broadcast ----------------
// N=8192 = 32 heads x 256 (128 k_nope | 128 v). Even col-tiles -> kfb (+kpe), odd -> vtb.
__global__ __launch_bounds__(256) void gemm_kvb(const short* __restrict__ A,
                                                const short* __restrict__ Bt,
                                                const short* __restrict__ kpe_bf,
                                                short* __restrict__ kfb,
                                                short* __restrict__ vtb) {
  const int K = KLL;
  __shared__ short As[64 * 64];
  __shared__ short Bs[128 * 64];
  __shared__ short tr[128 * 66];
  int flat = blockIdx.x + gridDim.x * blockIdx.y;
  flat = xcd_swz(flat, gridDim.x * gridDim.y);
  const int byg = flat % gridDim.y;
  const int bxg = flat / gridDim.y;
  const int tid = threadIdx.x;
  const int lane = tid & 63, wv = tid >> 6;
  const int wc = wv * 32;
  const int bm = byg * 64, bn = bxg * 128;
  const int l15 = lane & 15, l4 = lane >> 4;
  const int sx = (l15 & 7) * 8;
  f32x4 acc[4][2];
#pragma unroll
  for (int i = 0; i < 4; ++i)
#pragma unroll
    for (int j = 0; j < 2; ++j) acc[i][j] = f32x4{0.f, 0.f, 0.f, 0.f};
  for (int k0 = 0; k0 < K; k0 += 64) {
    __syncthreads();
#pragma unroll
    for (int i = 0; i < 2; ++i) {
      const int idx = tid + i * 256;
      const int row = idx >> 3, c8 = (idx & 7) * 8;
      const int cs = c8 ^ ((row & 7) * 8);
      gl16(A + (size_t)(bm + row) * K + k0 + cs, &As[idx * 8]);
    }
#pragma unroll
    for (int i = 0; i < 4; ++i) {
      const int idx = tid + i * 256;
      const int row = idx >> 3, c8 = (idx & 7) * 8;
      const int cs = c8 ^ ((row & 7) * 8);
      gl16(Bt + (size_t)(bn + row) * K + k0 + cs, &Bs[idx * 8]);
    }
    __syncthreads();
    short8 fa[4][2], fb[2][2];
#pragma unroll
    for (int rt = 0; rt < 4; ++rt)
#pragma unroll
      for (int kk = 0; kk < 2; ++kk)
        fa[rt][kk] = *(const short8*)(&As[(rt * 16 + l15) * 64 + ((kk * 32 + l4 * 8) ^ sx)]);
#pragma unroll
    for (int ct = 0; ct < 2; ++ct)
#pragma unroll
      for (int kk = 0; kk < 2; ++kk)
        fb[ct][kk] = *(const short8*)(&Bs[(wc + ct * 16 + l15) * 64 + ((kk * 32 + l4 * 8) ^ sx)]);
#pragma unroll
    for (int kk = 0; kk < 2; ++kk)
#pragma unroll
      for (int rt = 0; rt < 4; ++rt)
#pragma unroll
        for (int ct = 0; ct < 2; ++ct)
          acc[rt][ct] = __builtin_amdgcn_mfma_f32_16x16x32_bf16(fa[rt][kk], fb[ct][kk], acc[rt][ct], 0, 0, 0);
  }
  const int h = bn >> 8;
  const bool isv = (bn >> 7) & 1;
  if (!isv) {
    // k_nope: kfb[h][row][d], d = wc+ct*16+l15 in 0..127
#pragma unroll
    for (int rt = 0; rt < 4; ++rt)
#pragma unroll
      for (int ct = 0; ct < 2; ++ct)
#pragma unroll
        for (int r = 0; r < 4; ++r) {
          const int row = bm + rt * 16 + l4 * 4 + r;
          const int d = wc + ct * 16 + l15;
          kfb[((size_t)h * 1024 + row) * 192 + d] = f2bf(acc[rt][ct][r]);
        }
    // kpe broadcast: rows bm..bm+63, cols 128..191
#pragma unroll
    for (int i = 0; i < 2; ++i) {
      const int idx = tid + i * 256;         // 512 chunks = 64 rows x 8 chunks
      const int row = idx >> 3, c = idx & 7;
      *(short8*)(kfb + ((size_t)h * 1024 + bm + row) * 192 + 128 + c * 8) =
          *(const short8*)(kpe_bf + (size_t)(bm + row) * 64 + c * 8);
    }
  } else {
    // v: LDS transpose then vtb[h][d][k] coalesced along k
    __syncthreads();
#pragma unroll
    for (int rt = 0; rt < 4; ++rt)
#pragma unroll
      for (int ct = 0; ct < 2; ++ct)
#pragma unroll
        for (int r = 0; r < 4; ++r)
          tr[(wc + ct * 16 + l15) * 66 + rt * 16 + l4 * 4 + r] = f2bf(acc[rt][ct][r]);
    __syncthreads();
    const int d = tid >> 1, half = tid & 1;
    short* dst = vtb + ((size_t)h * 128 + d) * 1024 + bm + half * 32;
#pragma unroll
    for (int c = 0; c < 4; ++c) {
      short8 o;
#pragma unroll
      for (int e = 0; e < 8; ++e) o[e] = tr[d * 66 + half * 32 + c * 8 + e];
      *(short8*)(dst + c * 8) = o;
    }
  }
}

// ---------------- plain bf16 split-K GEMM -> fp32 partials ----------
__global__ __launch_bounds__(256) void gemm1_splitk(const short* __restrict__ A,
                                                    const short* __restrict__ Bt,
                                                    float* __restrict__ part,
                                                    int M, int Np, int K, int kchunk) {
  __shared__ short As[64 * 64];
  __shared__ short Bs[128 * 64];
  int flat = blockIdx.x + gridDim.x * (blockIdx.y + gridDim.y * blockIdx.z);
  flat = xcd_swz(flat, gridDim.x * gridDim.y * gridDim.z);
  const int byg = flat % gridDim.y;
  int tmp = flat / gridDim.y;
  const int bxg = tmp % gridDim.x, bzg = tmp / gridDim.x;
  const int tid = threadIdx.x;
  const int lane = tid & 63, wv = tid >> 6;
  const int wc = wv * 32;
  const int bm = byg * 64, bn = bxg * 128;
  const int kbeg = bzg * kchunk;
  const int l15 = lane & 15, l4 = lane >> 4;
  const int sx = (l15 & 7) * 8;
  f32x4 acc[4][2];
#pragma unroll
  for (int i = 0; i < 4; ++i)
#pragma unroll
    for (int j = 0; j < 2; ++j) acc[i][j] = f32x4{0.f, 0.f, 0.f, 0.f};
  for (int k0 = kbeg; k0 < kbeg + kchunk; k0 += 64) {
    __syncthreads();
#pragma unroll
    for (int i = 0; i < 2; ++i) {
      const int idx = tid + i * 256;
      const int row = idx >> 3, c8 = (idx & 7) * 8;
      const int cs = c8 ^ ((row & 7) * 8);
      gl16(A + (size_t)(bm + row) * K + k0 + cs, &As[idx * 8]);
    }
#pragma unroll
    for (int i = 0; i < 4; ++i) {
      const int idx = tid + i * 256;
      const int row = idx >> 3, c8 = (idx & 7) * 8;
      const int cs = c8 ^ ((row & 7) * 8);
      gl16(Bt + (size_t)(bn + row) * K + k0 + cs, &Bs[idx * 8]);
    }
    __syncthreads();
    short8 fa[4][2], fb[2][2];
#pragma unroll
    for (int rt = 0; rt < 4; ++rt)
#pragma unroll
      for (int kk = 0; kk < 2; ++kk)
        fa[rt][kk] = *(const short8*)(&As[(rt * 16 + l15) * 64 + ((kk * 32 + l4 * 8) ^ sx)]);
#pragma unroll
    for (int ct = 0; ct < 2; ++ct)
#pragma unroll
      for (int kk = 0; kk < 2; ++kk)
        fb[ct][kk] = *(const short8*)(&Bs[(wc + ct * 16 + l15) * 64 + ((kk * 32 + l4 * 8) ^ sx)]);
#pragma unroll
    for (int kk = 0; kk < 2; ++kk)
#pragma unroll
      for (int rt = 0; rt < 4; ++rt)
#pragma unroll
        for (int ct = 0; ct < 2; ++ct)
          acc[rt][ct] = __builtin_amdgcn_mfma_f32_16x16x32_bf16(fa[rt][kk], fb[ct][kk], acc[rt][ct], 0, 0, 0);
  }
  float* dst = part + (size_t)bzg * M * Np;
#pragma unroll
  for (int rt = 0; rt < 4; ++rt)
#pragma unroll
    for (int ct = 0; ct < 2; ++ct)
#pragma unroll
      for (int r = 0; r < 4; ++r)
        dst[(size_t)(bm + rt * 16 + l4 * 4 + r) * Np + bn + wc + ct * 16 + l15] =
            acc[rt][ct][r];
}

// ---------------- deterministic split-K reduce -> fp32 C ----------------
__global__ __launch_bounds__(256) void reduce_splitk(const float* __restrict__ part,
                                                     float* __restrict__ C,
                                                     int M, int Np, int ksplit) {
  const int c = blockIdx.x * 256 + threadIdx.x;
  const int m = blockIdx.y;
  float s = 0.f;
  for (int z = 0; z < ksplit; ++z) s += part[((size_t)z * M + m) * Np + c];
  C[(size_t)m * Np + c] = s;
}

// ---------------- pre-split bf16x3 GEMM, optional split-K ----------------
// BM=64, BK=32, hi/lo fused in [.][64] rows (cols 0-31 hi, 32-63 lo); T2 swizzle.
__global__ __launch_bounds__(256) void gemm3(const short* __restrict__ Ah,
                                             const short* __restrict__ Al,
                                             const short* __restrict__ Bth,
                                             const short* __restrict__ Btl,
                                             float* __restrict__ part,
                                             int M, int Np, int K, int kchunk) {
  __shared__ short AS[64 * 64], BS[128 * 64];
  int flat = blockIdx.x + gridDim.x * (blockIdx.y + gridDim.y * blockIdx.z);
  flat = xcd_swz(flat, gridDim.x * gridDim.y * gridDim.z);
  const int byg = flat % gridDim.y;
  int tmp = flat / gridDim.y;
  const int bxg = tmp % gridDim.x, bzg = tmp / gridDim.x;
  const int tid = threadIdx.x;
  const int lane = tid & 63, wv = tid >> 6;
  const int wc = wv * 32;
  const int l15 = lane & 15, l4 = lane >> 4;
  const int sx = (l15 & 7) * 8;
  const int bm = byg * 64, bn = bxg * 128;
  const int kbeg = bzg * kchunk;
  f32x4 acc[4][2];
#pragma unroll
  for (int i = 0; i < 4; ++i)
#pragma unroll
    for (int j = 0; j < 2; ++j) acc[i][j] = f32x4{0.f, 0.f, 0.f, 0.f};
  for (int k0 = kbeg; k0 < kbeg + kchunk; k0 += 32) {
    __syncthreads();
#pragma unroll
    for (int i = 0; i < 2; ++i) {              // A fused: 64 rows x 8 chunks
      const int idx = tid + i * 256;
      const int row = idx >> 3, c8 = (idx & 7) * 8;
      const int cs = c8 ^ ((row & 7) * 8);     // logical fused col
      const short* srcA = (cs < 32) ? (Ah + (size_t)(bm + row) * K + k0 + cs)
                                    : (Al + (size_t)(bm + row) * K + k0 + (cs - 32));
      gl16(srcA, &AS[idx * 8]);
    }
#pragma unroll
    for (int i = 0; i < 4; ++i) {              // B fused: 128 rows x 8 chunks
      const int idx = tid + i * 256;
      const int row = idx >> 3, c8 = (idx & 7) * 8;
      const int cs = c8 ^ ((row & 7) * 8);
      const short* srcB = (cs < 32) ? (Bth + (size_t)(bn + row) * K + k0 + cs)
                                    : (Btl + (size_t)(bn + row) * K + k0 + (cs - 32));
      gl16(srcB, &BS[idx * 8]);
    }
    __syncthreads();
    short8 fah[4], fal[4], fbh[2], fbl[2];
#pragma unroll
    for (int rt = 0; rt < 4; ++rt) {
      const int row = rt * 16 + l15;
      fah[rt] = *(const short8*)&AS[row * 64 + ((l4 * 8) ^ sx)];
      fal[rt] = *(const short8*)&AS[row * 64 + ((32 + l4 * 8) ^ sx)];
    }
#pragma unroll
    for (int ct = 0; ct < 2; ++ct) {
      const int row = wc + ct * 16 + l15;
      fbh[ct] = *(const short8*)&BS[row * 64 + ((l4 * 8) ^ sx)];
      fbl[ct] = *(const short8*)&BS[row * 64 + ((32 + l4 * 8) ^ sx)];
    }
#pragma unroll
    for (int ct = 0; ct < 2; ++ct)
#pragma unroll
      for (int rt = 0; rt < 4; ++rt) {
        acc[rt][ct] = __builtin_amdgcn_mfma_f32_16x16x32_bf16(fah[rt], fbh[ct], acc[rt][ct], 0, 0, 0);
        acc[rt][ct] = __builtin_amdgcn_mfma_f32_16x16x32_bf16(fah[rt], fbl[ct], acc[rt][ct], 0, 0, 0);
        acc[rt][ct] = __builtin_amdgcn_mfma_f32_16x16x32_bf16(fal[rt], fbh[ct], acc[rt][ct], 0, 0, 0);
      }
  }
  float* dst = part + (size_t)bzg * M * Np;
#pragma unroll
  for (int rt = 0; rt < 4; ++rt)
#pragma unroll
    for (int ct = 0; ct < 2; ++ct)
#pragma unroll
      for (int r = 0; r < 4; ++r)
        dst[(size_t)(bm + rt * 16 + l4 * 4 + r) * Np + bn + wc + ct * 16 + l15] =
            acc[rt][ct][r];
}

// ---------------- fused qkv epilogue: split-K reduce + 2x RMS + kpe rope -> bf16 ------
__global__ __launch_bounds__(256) void qkv_post(const float* __restrict__ qpart,
                                                const float* __restrict__ tpart,
                                                const float* __restrict__ q_ln_w,
                                                const float* __restrict__ kv_ln_w,
                                                const float* __restrict__ ropeC,
                                                const float* __restrict__ ropeS,
                                                short* __restrict__ qcn_bf,
                                                short* __restrict__ qcn_lo,
                                                short* __restrict__ kvn_bf,
                                                short* __restrict__ kpe_bf) {
  const int t = blockIdx.x, tid = threadIdx.x;
  __shared__ float red[4];
  float qv[6];
  float ss = 0.f;
#pragma unroll
  for (int j = 0; j < 6; ++j) {
    const int c = tid + j * 256;
    float s = 0.f;
#pragma unroll
    for (int z = 0; z < 4; ++z) s += qpart[((size_t)z * TT + t) * QLL + c];
    qv[j] = s;
    ss = fmaf(s, s, ss);
  }
#pragma unroll
  for (int o = 32; o > 0; o >>= 1) ss += __shfl_xor(ss, o);
  if ((tid & 63) == 0) red[tid >> 6] = ss;
  __syncthreads();
  const float rq = rsqrtf((red[0] + red[1] + red[2] + red[3]) / (float)QLL + 1e-6f);
  __syncthreads();
#pragma unroll
  for (int j = 0; j < 6; ++j) {
    const int c = tid + j * 256;
    const float v = qv[j] * rq * q_ln_w[c];
    const short h = f2bf(v);
    qcn_bf[(size_t)t * QLL + c] = h;
    qcn_lo[(size_t)t * QLL + c] = f2bf(v - bf2f(h));
  }
  float kv2[2];
  float ss2 = 0.f;
#pragma unroll
  for (int j = 0; j < 2; ++j) {
    const int c = tid + j * 256;
    float s = 0.f;
#pragma unroll
    for (int z = 0; z < 4; ++z) s += tpart[((size_t)z * TT + t) * 640 + c];
    kv2[j] = s;
    ss2 = fmaf(s, s, ss2);
  }
#pragma unroll
  for (int o = 32; o > 0; o >>= 1) ss2 += __shfl_xor(ss2, o);
  if ((tid & 63) == 0) red[tid >> 6] = ss2;
  __syncthreads();
  const float rkv = rsqrtf((red[0] + red[1] + red[2] + red[3]) / (float)KLL + 1e-6f);
#pragma unroll
  for (int j = 0; j < 2; ++j) {
    const int c = tid + j * 256;
    kvn_bf[(size_t)t * KLL + c] = f2bf(kv2[j] * rkv * kv_ln_w[c]);
  }
  if (tid < 32) {
    float x1 = 0.f, x2 = 0.f;
#pragma unroll
    for (int z = 0; z < 4; ++z) {
      x1 += tpart[((size_t)z * TT + t) * 640 + 512 + 2 * tid];
      x2 += tpart[((size_t)z * TT + t) * 640 + 512 + 2 * tid + 1];
    }
    const float cs = ropeC[t * 32 + tid];
    const float sn = ropeS[t * 32 + tid];
    kpe_bf[(size_t)t * 64 + 2 * tid]     = f2bf(x1 * cs - x2 * sn);
    kpe_bf[(size_t)t * 64 + 2 * tid + 1] = f2bf(x1 * sn + x2 * cs);
  }
}

// ---------------- fused ki epilogue: z-sum + LN + RoPE + hi/lo split + wtsb -----------
__global__ __launch_bounds__(256) void ki_prep2(const float* __restrict__ part,
                                                const float* __restrict__ w,
                                                const float* __restrict__ b,
                                                const float* __restrict__ ropeC,
                                                const float* __restrict__ ropeS,
                                                short* __restrict__ kih,
                                                short* __restrict__ kil,
                                                float* __restrict__ wtsb) {
  const int t = blockIdx.x, tid = threadIdx.x;
  __shared__ float red[4], red2[4];
  float s = 0.f;
#pragma unroll
  for (int z = 0; z < 8; ++z) s += part[((size_t)z * TT + t) * 256 + tid];
  if (tid >= 128 && tid < 160) wtsb[(size_t)t * 32 + (tid - 128)] = s;
  const float v = (tid < 128) ? s : 0.f;
  float sm = v;
#pragma unroll
  for (int o = 32; o > 0; o >>= 1) sm += __shfl_xor(sm, o);
  if ((tid & 63) == 0) red[tid >> 6] = sm;
  __syncthreads();
  const float m = (red[0] + red[1]) * (1.f / 128.f);
  const float dv = v - m;
  float sq = (tid < 128) ? dv * dv : 0.f;
#pragma unroll
  for (int o = 32; o > 0; o >>= 1) sq += __shfl_xor(sq, o);
  if ((tid & 63) == 0) red2[tid >> 6] = sq;
  __syncthreads();
  const float var = (red2[0] + red2[1]) * (1.f / 128.f);
  if (tid < 128) {
    float x = dv * rsqrtf(var + 1e-6f) * w[tid] + b[tid];
    if (tid < 64) {
      const float part2 = __shfl_xor(x, 1);
      const int pi = tid >> 1;
      const float cs = ropeC[t * 32 + pi];
      const float sn = ropeS[t * 32 + pi];
      x = (tid & 1) ? (part2 * sn + x * cs) : (x * cs - part2 * sn);
    }
    const short h = f2bf(x);
    kih[(size_t)t * 128 + tid] = h;
    kil[(size_t)t * 128 + tid] = f2bf(x - bf2f(h));
  }
}

// ---------------- f32 -> bf16 hi/lo split (flat) ----------------
__global__ __launch_bounds__(256) void split_cast(const float* __restrict__ in,
                                                  short* __restrict__ hi,
                                                  short* __restrict__ lo, int n4) {
  const int i = blockIdx.x * 256 + threadIdx.x;
  if (i >= n4) return;
  float4 v = *(const float4*)(in + (size_t)i * 4);
  float av[4] = {v.x, v.y, v.z, v.w};
  short4v h, l;
#pragma unroll
  for (int e = 0; e < 4; ++e) {
    h[e] = f2bf(av[e]);
    l[e] = f2bf(av[e] - bf2f(h[e]));
  }
  *(short4v*)(hi + (size_t)i * 4) = h;
  *(short4v*)(lo + (size_t)i * 4) = l;
}

// ---------------- generalized transpose+cast: Bt[n][k] = bf16(B[k][col0+n]) ----------
__global__ __launch_bounds__(256) void transpose_cast_g(const float* __restrict__ B,
                                                        short* __restrict__ Bt,
                                                        int K, int ldB, int col0, int Ncols) {
  __shared__ float tile[64][65];
  const int tid = threadIdx.x;
  const int k0 = blockIdx.y * 64, n0 = blockIdx.x * 64;
  const int nl = tid >> 3, kc = (tid & 7) * 8;
  if (n0 >= Ncols) {
    short8 z = {0, 0, 0, 0, 0, 0, 0, 0};
#pragma unroll
    for (int i = 0; i < 2; ++i) {
      const int n = nl + i * 32;
      *(short8*)(Bt + (size_t)(n0 + n) * K + k0 + kc) = z;
    }
    return;
  }
  const int r = tid >> 4, c4 = (tid & 15) * 4;
#pragma unroll
  for (int i = 0; i < 4; ++i) {
    float4 v = *(const float4*)(B + (size_t)(k0 + r + i * 16) * ldB + col0 + n0 + c4);
    tile[r + i * 16][c4 + 0] = v.x;
    tile[r + i * 16][c4 + 1] = v.y;
    tile[r + i * 16][c4 + 2] = v.z;
    tile[r + i * 16][c4 + 3] = v.w;
  }
  __syncthreads();
#pragma unroll
  for (int i = 0; i < 2; ++i) {
    const int n = nl + i * 32;
    short8 o;
#pragma unroll
    for (int e = 0; e < 8; ++e) o[e] = f2bf(tile[kc + e][n]);
    *(short8*)(Bt + (size_t)(n0 + n) * K + k0 + kc) = o;
  }
}

// ---------------- generalized transpose + hi/lo split cast (partial-tile safe) -------
__global__ __launch_bounds__(256) void transpose_split_cast(const float* __restrict__ B,
                                                            short* __restrict__ Bth,
                                                            short* __restrict__ Btl,
                                                            int K, int ldB, int col0,
                                                            int Ncols) {
  __shared__ float tile[64][65];
  const int tid = threadIdx.x;
  const int k0 = blockIdx.y * 64, n0 = blockIdx.x * 64;
  const int nl = tid >> 3, kc = (tid & 7) * 8;
  if (n0 >= Ncols) {
    short8 z = {0, 0, 0, 0, 0, 0, 0, 0};
#pragma unroll
    for (int i = 0; i < 2; ++i) {
      const int n = nl + i * 32;
      *(short8*)(Bth + (size_t)(n0 + n) * K + k0 + kc) = z;
      *(short8*)(Btl + (size_t)(n0 + n) * K + k0 + kc) = z;
    }
    return;
  }
  const int r = tid >> 4, c4 = (tid & 15) * 4;
#pragma unroll
  for (int i = 0; i < 4; ++i) {
    float4 v = make_float4(0.f, 0.f, 0.f, 0.f);
    if (n0 + c4 < Ncols)
      v = *(const float4*)(B + (size_t)(k0 + r + i * 16) * ldB + col0 + n0 + c4);
    tile[r + i * 16][c4 + 0] = v.x;
    tile[r + i * 16][c4 + 1] = v.y;
    tile[r + i * 16][c4 + 2] = v.z;
    tile[r + i * 16][c4 + 3] = v.w;
  }
  __syncthreads();
#pragma unroll
  for (int i = 0; i < 2; ++i) {
    const int n = nl + i * 32;
    short8 oh, ol;
#pragma unroll
    for (int e = 0; e < 8; ++e) {
      const float x = tile[kc + e][n];
      oh[e] = f2bf(x);
      ol[e] = f2bf(x - bf2f(oh[e]));
    }
    *(short8*)(Bth + (size_t)(n0 + n) * K + k0 + kc) = oh;
    *(short8*)(Btl + (size_t)(n0 + n) * K + k0 + kc) = ol;
  }
}

// ---------------- MFMA indexer logits: triangular grid + XCD swizzle, 8 heads/plane ----
__global__ __launch_bounds__(256) void logits_mfma(const short* __restrict__ qih,
                                                   const short* __restrict__ qil,
                                                   const short* __restrict__ kih_g,
                                                   const short* __restrict__ kil_g,
                                                   const float* __restrict__ wts,
                                                   float* __restrict__ part) {
  const int bid = xcd_swz(blockIdx.x, gridDim.x);
  int bq = (int)((sqrtf(8.f * bid + 1.f) - 1.f) * 0.5f);
  while ((bq + 1) * (bq + 2) / 2 <= bid) ++bq;
  while (bq * (bq + 1) / 2 > bid) --bq;
  const int bk = bid - bq * (bq + 1) / 2;
  const int g = blockIdx.y;  // 0..3 (8 heads each)
  __shared__ short kih[64 * 128], kil[64 * 128];
  __shared__ float swts[64][8];
  const int tid = threadIdx.x;
  const int lane = tid & 63, wv = tid >> 6;
  const int wr = (wv >> 1) * 32, wc = (wv & 1) * 32;
  const int l15 = lane & 15, l4 = lane >> 4;
  const int q0 = bq * 64, k0 = bk * 64;
  {
    const int r0 = tid >> 4;
    const int c8 = (tid & 15) * 8;
#pragma unroll
    for (int i = 0; i < 4; ++i) {
      const int row = r0 + i * 16;
      gl16(kih_g + (size_t)(k0 + row) * 128 + c8, &kih[(tid + i * 256) * 8]);
      gl16(kil_g + (size_t)(k0 + row) * 128 + c8, &kil[(tid + i * 256) * 8]);
    }
  }
#pragma unroll
  for (int i = 0; i < 2; ++i) {
    const int idx = tid + i * 256;
    swts[idx >> 3][idx & 7] = wts[(size_t)(q0 + (idx >> 3)) * 32 + g * 8 + (idx & 7)];
  }
  __syncthreads();
  short8 kbh[2][4], kbl[2][4];
#pragma unroll
  for (int ct = 0; ct < 2; ++ct)
#pragma unroll
    for (int ks = 0; ks < 4; ++ks) {
      kbh[ct][ks] = *(const short8*)&kih[(wc + ct * 16 + l15) * 128 + ks * 32 + l4 * 8];
      kbl[ct][ks] = *(const short8*)&kil[(wc + ct * 16 + l15) * 128 + ks * 32 + l4 * 8];
    }
  f32x4 lacc[2][2];
#pragma unroll
  for (int i = 0; i < 2; ++i)
#pragma unroll
    for (int j = 0; j < 2; ++j) lacc[i][j] = f32x4{0.f, 0.f, 0.f, 0.f};
  for (int hh = 0; hh < 8; ++hh) {
    const int h = g * 8 + hh;
    short8 qah[2][4], qal[2][4];
#pragma unroll
    for (int rt = 0; rt < 2; ++rt)
#pragma unroll
      for (int ks = 0; ks < 4; ++ks) {
        const size_t off = ((size_t)h * 1024 + q0 + wr + rt * 16 + l15) * 128 + ks * 32 + l4 * 8;
        qah[rt][ks] = *(const short8*)(qih + off);
        qal[rt][ks] = *(const short8*)(qil + off);
      }
    f32x4 hacc[2][2];
#pragma unroll
    for (int i = 0; i < 2; ++i)
#pragma unroll
      for (int j = 0; j < 2; ++j) hacc[i][j] = f32x4{0.f, 0.f, 0.f, 0.f};
#pragma unroll
    for (int ks = 0; ks < 4; ++ks)
#pragma unroll
      for (int rt = 0; rt < 2; ++rt)
#pragma unroll
        for (int ct = 0; ct < 2; ++ct) {
          hacc[rt][ct] = __builtin_amdgcn_mfma_f32_16x16x32_bf16(qah[rt][ks], kbh[ct][ks], hacc[rt][ct], 0, 0, 0);
          hacc[rt][ct] = __builtin_amdgcn_mfma_f32_16x16x32_bf16(qah[rt][ks], kbl[ct][ks], hacc[rt][ct], 0, 0, 0);
          hacc[rt][ct] = __builtin_amdgcn_mfma_f32_16x16x32_bf16(qal[rt][ks], kbh[ct][ks], hacc[rt][ct], 0, 0, 0);
        }
#pragma unroll
    for (int rt = 0; rt < 2; ++rt)
#pragma unroll
      for (int ct = 0; ct < 2; ++ct)
#pragma unroll
        for (int r = 0; r < 4; ++r) {
          const int row = wr + rt * 16 + l4 * 4 + r;
          const float w = swts[row][hh] * kWtsScale;
          lacc[rt][ct][r] = fmaf(w, fmaxf(hacc[rt][ct][r], 0.f), lacc[rt][ct][r]);
        }
  }
#pragma unroll
  for (int rt = 0; rt < 2; ++rt)
#pragma unroll
    for (int ct = 0; ct < 2; ++ct)
#pragma unroll
      for (int r = 0; r < 4; ++r)
        part[(size_t)g * TT * TT + (size_t)(q0 + wr + rt * 16 + l4 * 4 + r) * TT +
             (k0 + wc + ct * 16 + l15)] = lacc[rt][ct][r];
}

// ---------------- top-512 -> bitmask: ballot-based, one wave per q-row (4 planes) ------
__global__ __launch_bounds__(256) void topk_mask(const float* __restrict__ part,
                                                 unsigned* __restrict__ maskbuf) {
  const int w = threadIdx.x >> 6;
  const int lane = threadIdx.x & 63;
  const int q = blockIdx.x * 4 + w;
  const size_t NN = (size_t)TT * TT;
  __shared__ unsigned long long bl[4][16];
  unsigned v[16];
#pragma unroll
  for (int j = 0; j < 16; ++j) {
    const int k = j * 64 + lane;
    unsigned uv = 0u;
    if (k <= q) {
      const size_t o = (size_t)q * TT + k;
      const float s = part[o] + part[NN + o] + part[2 * NN + o] + part[3 * NN + o];
      unsigned bb = __float_as_uint(s);
      uv = (bb & 0x80000000u) ? ~bb : (bb | 0x80000000u);
    }
    v[j] = uv;
  }
  if (q + 1 <= TOPKK) {
#pragma unroll
    for (int j = 0; j < 16; ++j) {
      const unsigned long long m = __ballot(j * 64 + lane <= q);
      if (lane == 0) bl[w][j] = m;
    }
  } else {
    unsigned lo = 1u, hi = 0xFFFFFFFFu;
    while (lo < hi) {
      const unsigned mid = lo + ((hi - lo) >> 1) + ((hi - lo) & 1u);
      int c = 0;
#pragma unroll
      for (int j = 0; j < 16; ++j) c += __popcll(__ballot(v[j] >= mid));
      if (c >= TOPKK) lo = mid; else hi = mid - 1u;
    }
    const unsigned ustar = lo;
    int nGreater = 0;
#pragma unroll
    for (int j = 0; j < 16; ++j) nGreater += __popcll(__ballot(v[j] > ustar));
    int need = TOPKK - nGreater;
    const unsigned long long lanemask = lane ? (~0ull >> (64 - lane)) : 0ull;
#pragma unroll
    for (int j = 0; j < 16; ++j) {
      const unsigned long long bg = __ballot(v[j] > ustar);
      const unsigned long long be = __ballot(v[j] == ustar);
      const int ce = __popcll(be);
      const int take = need < ce ? need : ce;
      const int rank = __popcll(be & lanemask);
      const bool selme = ((be >> lane) & 1ull) && (rank < take);
      const unsigned long long m = bg | __ballot(selme);
      if (lane == 0) bl[w][j] = m;
      need -= take;
    }
  }
  __builtin_amdgcn_s_waitcnt(0);
  if (lane < 32)
    maskbuf[(size_t)q * 32 + lane] = (unsigned)(bl[w][lane >> 1] >> ((lane & 1) * 32));
}

// ---------------- masked dense MFMA attention ----------------
__global__ __launch_bounds__(256) void attn_mfma(const short* __restrict__ qh,
                                                 const short* __restrict__ kf,
                                                 const short* __restrict__ vt,
                                                 const unsigned* __restrict__ maskbuf,
                                                 short* __restrict__ ao) {
  const int h = blockIdx.x;
  const int yy = blockIdx.y;
  const int qt = (yy < 8) ? (yy * 2) : (31 - yy * 2);
  const int tid = threadIdx.x;
  const int lane = tid & 63, w = tid >> 6;
  const int l15 = lane & 15, l4 = lane >> 4;
  const int q0 = qt * 64;
  __shared__ short kfs[64 * 200];
  __shared__ short vts[128 * 72];
  __shared__ short ps[4][16][72];
  __shared__ unsigned m32s[64][2];
  short8 qf[6];
#pragma unroll
  for (int ks = 0; ks < 6; ++ks)
    qf[ks] = *(const short8*)(qh + ((size_t)h * 1024 + q0 + w * 16 + l15) * 192 + ks * 32 + l4 * 8);
  f32x4 of[8];
#pragma unroll
  for (int dt = 0; dt < 8; ++dt) of[dt] = f32x4{0.f, 0.f, 0.f, 0.f};
  float m[4], l[4];
#pragma unroll
  for (int r = 0; r < 4; ++r) { m[r] = -INFINITY; l[r] = 0.f; }

  for (int kt = 0; kt <= qt; ++kt) {
    const int k0 = kt * 64;
    __syncthreads();
#pragma unroll
    for (int i = 0; i < 6; ++i) {
      const int idx = tid + i * 256;
      const int row = idx / 24, c = idx - row * 24;
      *(short8*)&kfs[row * 200 + c * 8] =
          *(const short8*)(kf + ((size_t)h * 1024 + k0 + row) * 192 + c * 8);
    }
#pragma unroll
    for (int i = 0; i < 4; ++i) {
      const int idx = tid + i * 256;
      const int row = idx >> 3, c = idx & 7;
      *(short8*)&vts[row * 72 + c * 8] =
          *(const short8*)(vt + ((size_t)h * 128 + row) * 1024 + k0 + c * 8);
    }
    if (tid < 128)
      m32s[tid >> 1][tid & 1] = maskbuf[(size_t)(q0 + (tid >> 1)) * 32 + (k0 >> 5) + (tid & 1)];
    __syncthreads();
    f32x4 sacc[4];
#pragma unroll
    for (int j = 0; j < 4; ++j) sacc[j] = f32x4{0.f, 0.f, 0.f, 0.f};
#pragma unroll
    for (int ks = 0; ks < 6; ++ks)
#pragma unroll
      for (int j = 0; j < 4; ++j) {
        short8 kb = *(const short8*)&kfs[(j * 16 + l15) * 200 + ks * 32 + l4 * 8];
        sacc[j] = __builtin_amdgcn_mfma_f32_16x16x32_bf16(qf[ks], kb, sacc[j], 0, 0, 0);
      }
    float tmax[4] = {-INFINITY, -INFINITY, -INFINITY, -INFINITY};
#pragma unroll
    for (int j = 0; j < 4; ++j)
#pragma unroll
      for (int r = 0; r < 4; ++r) {
        const int kcol = j * 16 + l15;
        const unsigned um = m32s[w * 16 + l4 * 4 + r][kcol >> 5];
        float s = sacc[j][r] * kScaling;
        s = ((um >> (kcol & 31)) & 1u) ? s : -INFINITY;
        sacc[j][r] = s;
        tmax[r] = fmaxf(tmax[r], s);
      }
#pragma unroll
    for (int r = 0; r < 4; ++r) {
      tmax[r] = fmaxf(tmax[r], __shfl_xor(tmax[r], 1));
      tmax[r] = fmaxf(tmax[r], __shfl_xor(tmax[r], 2));
      tmax[r] = fmaxf(tmax[r], __shfl_xor(tmax[r], 4));
      tmax[r] = fmaxf(tmax[r], __shfl_xor(tmax[r], 8));
    }
    float f[4];
#pragma unroll
    for (int r = 0; r < 4; ++r) {
      const float mn = fmaxf(m[r], tmax[r]);
      f[r] = __expf(fmaxf(m[r], -1e30f) - fmaxf(mn, -1e30f));
      m[r] = mn;
      l[r] *= f[r];
    }
    float psum[4] = {0.f, 0.f, 0.f, 0.f};
#pragma unroll
    for (int j = 0; j < 4; ++j)
#pragma unroll
      for (int r = 0; r < 4; ++r) {
        const float p = __expf(sacc[j][r] - fmaxf(m[r], -1e30f));
        psum[r] += p;
        ps[w][l4 * 4 + r][j * 16 + l15] = f2bf(p);
      }
#pragma unroll
    for (int r = 0; r < 4; ++r) {
      psum[r] += __shfl_xor(psum[r], 1);
      psum[r] += __shfl_xor(psum[r], 2);
      psum[r] += __shfl_xor(psum[r], 4);
      psum[r] += __shfl_xor(psum[r], 8);
      l[r] += psum[r];
    }
#pragma unroll
    for (int dt = 0; dt < 8; ++dt)
#pragma unroll
      for (int r = 0; r < 4; ++r) of[dt][r] *= f[r];
    short8 pa0 = *(const short8*)&ps[w][l15][l4 * 8];
    short8 pa1 = *(const short8*)&ps[w][l15][32 + l4 * 8];
#pragma unroll
    for (int dt = 0; dt < 8; ++dt) {
      short8 vb0 = *(const short8*)&vts[(dt * 16 + l15) * 72 + l4 * 8];
      short8 vb1 = *(const short8*)&vts[(dt * 16 + l15) * 72 + 32 + l4 * 8];
      of[dt] = __builtin_amdgcn_mfma_f32_16x16x32_bf16(pa0, vb0, of[dt], 0, 0, 0);
      of[dt] = __builtin_amdgcn_mfma_f32_16x16x32_bf16(pa1, vb1, of[dt], 0, 0, 0);
    }
  }
#pragma unroll
  for (int r = 0; r < 4; ++r) {
    const float invl = 1.f / l[r];
#pragma unroll
    for (int dt = 0; dt < 8; ++dt)
      ao[(size_t)(q0 + w * 16 + l4 * 4 + r) * 4096 + h * 128 + dt * 16 + l15] =
          f2bf(of[dt][r] * invl);
  }
}

// ============================================================================
extern "C" void kernel_launch(void* const* d_in, const int* in_sizes, int n_in,
                              void* d_out, int out_size, void* d_ws, size_t ws_size,
                              hipStream_t stream) {
  const float* hidden     = (const float*)d_in[0];
  const int*   positions  = (const int*)d_in[1];
  const float* w_qkv_a    = (const float*)d_in[2];
  const float* q_a_ln_w   = (const float*)d_in[3];
  const float* w_q_b      = (const float*)d_in[4];
  const float* kv_a_ln_w  = (const float*)d_in[5];
  const float* w_kv_b     = (const float*)d_in[6];
  const float* w_o        = (const float*)d_in[7];
  const float* w_idx_qb   = (const float*)d_in[8];
  const float* w_idx_k    = (const float*)d_in[9];
  const float* idx_k_ln_w = (const float*)d_in[10];
  const float* idx_k_ln_b = (const float*)d_in[11];
  const float* w_idx_w    = (const float*)d_in[12];
  float* out = (float*)d_out;

  float* ws = (float*)d_ws;
  size_t off = 0;
  auto take = [&](size_t n) { float* p = ws + off; off += n; return p; };
  short* qcn_bf  = (short*)take((size_t)TT * QLL / 2);
  short* qcn_lo  = (short*)take((size_t)TT * QLL / 2);
  short* kvn_bf  = (short*)take((size_t)TT * KLL / 2);
  short* kpe_bf  = (short*)take((size_t)TT * 32);
  float* wtsb    = take((size_t)TT * INHH);
  float* rope_ct = take((size_t)TT * 32);
  float* rope_st = take((size_t)TT * 32);
  short* kih_g   = (short*)take((size_t)TT * IHDD / 2);
  short* kil_g   = (short*)take((size_t)TT * IHDD / 2);
  short* qhb     = (short*)take((size_t)NHH * TT * 192 / 2);   // bf16 [h][q][192]
  short* kfb     = (short*)take((size_t)NHH * TT * 192 / 2);   // bf16 [h][k][192]
  short* vtb     = (short*)take((size_t)NHH * 128 * TT / 2);   // bf16 [h][d][k]
  short* qih_h   = (short*)take((size_t)INHH * TT * 128 / 2);
  short* qih_l   = (short*)take((size_t)INHH * TT * 128 / 2);
  float* part4   = take((size_t)4 * TT * TT);
  unsigned* maskbuf = (unsigned*)take((size_t)TT * 32);
  short* hid_h   = (short*)take((size_t)TT * HH / 2);
  short* hid_l   = (short*)take((size_t)TT * HH / 2);
  short* wqkva_h = (short*)take((size_t)QLL * HH / 2);
  short* wqkva_l = (short*)take((size_t)QLL * HH / 2);
  short* wtail_t = (short*)take((size_t)640 * HH / 2);
  short* wsk_h   = (short*)take((size_t)256 * HH / 2);
  short* wsk_l   = (short*)take((size_t)256 * HH / 2);
  short* widxqb_h = (short*)take((size_t)HH * QLL / 2);
  short* widxqb_l = (short*)take((size_t)HH * QLL / 2);
  short* wqb_t   = (short*)take((size_t)6144 * QLL / 2);
  short* wkvb_t  = (short*)take((size_t)8192 * KLL / 2);
  short* ao   = (short*)part4;       // alias: part4[0 .. 2.1M floats), dead after topk
  short* wo_t = hid_h;               // alias: hid dead after qkv gemms
  float* skpart = part4;             // alias: 8*1024*256 = 2.1M floats < part4 (not live yet)
  // qkvpart 4x1024x1536 = 6.29M floats = vtb(2.10M)+qih_h(2.10M)+qih_l(2.10M) floats exactly
  float* qkvpart = (float*)vtb;
  // tailpart 4x1024x640 = 2.62M floats < qhb (3.14M floats) — qhb written later by gemm_qb
  float* tailpart = (float*)qhb;
  // w_o split-K partials: 2x1024x4096 = 8.39M floats reusing the qhb..vtb span —
  // qhb/kfb/vtb are dead after attn_mfma; ao lives in part4 and wo_t in hid_h (no overlap).
  float* wopart = (float*)qhb;

  const dim3 blk(256);
  // rope table (only dep: positions)
  rope_tab<<<dim3(TT), 32, 0, stream>>>(positions, rope_ct, rope_st);
  // input/weight splits
  split_cast<<<dim3(TT * HH / 4 / 256), blk, 0, stream>>>(hidden, hid_h, hid_l, TT * HH / 4);
  transpose_split_cast<<<dim3(QLL / 64, HH / 64), blk, 0, stream>>>(w_qkv_a, wqkva_h, wqkva_l, HH, QKVN, 0, QLL);
  transpose_cast_g<<<dim3(640 / 64, HH / 64), blk, 0, stream>>>(w_qkv_a, wtail_t, HH, QKVN, QLL, QKVN - QLL);
  transpose_split_cast<<<dim3(HH / 64, QLL / 64), blk, 0, stream>>>(w_idx_qb, widxqb_h, widxqb_l, QLL, HH, 0, HH);
  transpose_split_cast<<<dim3(2, HH / 64), blk, 0, stream>>>(w_idx_k, wsk_h, wsk_l, HH, 128, 0, 128);
  transpose_split_cast<<<dim3(2, HH / 64), blk, 0, stream>>>(w_idx_w, wsk_h + (size_t)128 * HH,
                                                            wsk_l + (size_t)128 * HH, HH, 32, 0, 32);
  transpose_cast_g<<<dim3(6144 / 64, QLL / 64), blk, 0, stream>>>(w_q_b, wqb_t, QLL, 6144, 0, 6144);
  transpose_cast_g<<<dim3(8192 / 64, KLL / 64), blk, 0, stream>>>(w_kv_b, wkvb_t, KLL, 8192, 0, 8192);
  // skinny projections via bf16x3 MFMA z=8; partials in part4
  gemm3<<<dim3(2, 16, 8), blk, 0, stream>>>(hid_h, hid_l, wsk_h, wsk_l,
                                            skpart, TT, 256, HH, HH / 8);
  ki_prep2<<<dim3(TT), blk, 0, stream>>>(skpart, idx_k_ln_w, idx_k_ln_b, rope_ct, rope_st,
                                         kih_g, kil_g, wtsb);
  // qkv_a q_c: bf16x3 split-K z=4 -> qkvpart (vtb+qih span)
  gemm3<<<dim3(QLL / 128, 16, 4), blk, 0, stream>>>(hid_h, hid_l, wqkva_h, wqkva_l,
                                                    qkvpart, TT, QLL, HH, HH / 4);
  // qkv_a kv/kpe tail: z=4 -> tailpart (qhb span)
  gemm1_splitk<<<dim3(5, 16, 4), blk, 0, stream>>>(hid_h, wtail_t, tailpart, TT, 640, HH, HH / 4);
  // fused epilogue -> qcn hi/lo, kvn, kpe_bf
  qkv_post<<<dim3(TT), blk, 0, stream>>>(qkvpart, tailpart, q_a_ln_w, kv_a_ln_w,
                                         rope_ct, rope_st, qcn_bf, qcn_lo, kvn_bf, kpe_bf);
  // w_o transpose (hid region dead)
  transpose_cast_g<<<dim3(HH / 64, HH / 64), blk, 0, stream>>>(w_o, wo_t, HH, HH, 0, HH);
  // idx_qb: fused bf16x3 GEMM (BK=64, z=1) + rope/repack/split epilogue -> qih directly
  gemm_idx<<<dim3(HH / 128, 16), blk, 0, stream>>>(qcn_bf, qcn_lo, widxqb_h, widxqb_l,
                                                   rope_ct, rope_st, qih_h, qih_l);
  // smooth projections with fused repacks
  gemm_qb<<<dim3(48, 16), blk, 0, stream>>>(qcn_bf, wqb_t, rope_ct, rope_st, qhb);
  gemm_kvb<<<dim3(64, 16), blk, 0, stream>>>(kvn_bf, wkvb_t, kpe_bf, kfb, vtb);
  // indexer logits (triangular + XCD swizzle, 4 planes)
  logits_mfma<<<dim3(136, 4), blk, 0, stream>>>(qih_h, qih_l, kih_g, kil_g, wtsb, part4);
  // top-512 -> bitmask
  topk_mask<<<dim3(TT / 4), blk, 0, stream>>>(part4, maskbuf);
  // masked dense MFMA attention
  attn_mfma<<<dim3(NHH, 16), blk, 0, stream>>>(qhb, kfb, vtb, maskbuf, ao);
  // output projection: split-K z=2 (1024 blocks = 4/CU) + deterministic reduce
  gemm1_splitk<<<dim3(HH / 128, 16, 2), blk, 0, stream>>>(ao, wo_t, wopart, TT, HH,
                                                          NHH * DVV, NHH * DVV / 2);
  reduce_splitk<<<dim3(HH / 256, TT), blk, 0, stream>>>(wopart, out, TT, HH, 2);
}

// Round 25
// 451.110 us; speedup vs baseline: 1.0701x; 1.0089x over previous
//
#include <hip/hip_runtime.h>
#include <hip/hip_bf16.h>
#include <math.h>
#include <type_traits>

#define TT   1024
#define HH   4096
#define NHH  32
#define DNN  128
#define DRR  64
#define DVV  128
#define QLL  1536
#define KLL  512
#define INHH 32
#define IHDD 128
#define TOPKK 512
#define QKVN 2112

typedef __attribute__((ext_vector_type(8))) short short8;
typedef __attribute__((ext_vector_type(4))) short short4v;
typedef __attribute__((ext_vector_type(4))) float f32x4;

static __device__ __constant__ float kScaling = 0.07216878364870322f;  // (DN+DR)^-0.5
static __device__ __constant__ float kWtsScale = 0.015625f;            // IHD^-.5 * INH^-.5
#define LOG2_10000_OVER_32 0.4152410118609203f

static __device__ __forceinline__ short f2bf(float f) {
  unsigned u = __float_as_uint(f);
  unsigned r = (u + 0x7fffu + ((u >> 16) & 1u)) >> 16;  // RNE
  return (short)r;
}
static __device__ __forceinline__ float bf2f(short s) {
  return __uint_as_float(((unsigned)(unsigned short)s) << 16);
}
// async global->LDS, 16B per lane; lds dest must be wave-uniform base + lane*16
static __device__ __forceinline__ void gl16(const void* g, void* l) {
  __builtin_amdgcn_global_load_lds(
      (const __attribute__((address_space(1))) unsigned int*)g,
      (__attribute__((address_space(3))) unsigned int*)l, 16, 0, 0);
}
// XCD-aware bijective block remap (m204): dispatch slot n -> work id
static __device__ __forceinline__ int xcd_swz(int n, int nwg) {
  const int q = nwg >> 3, r = nwg & 7;
  const int x = n & 7, i = n >> 3;
  return (x < r ? x * (q + 1) : r * (q + 1) + (x - r) * q) + i;
}

// ---------------- rope cos/sin table: [t][i], i in 0..31 ----------------
__global__ void rope_tab(const int* __restrict__ pos,
                         float* __restrict__ ct, float* __restrict__ st) {
  const int t = blockIdx.x, i = threadIdx.x;  // 32 threads
  const float inv = exp2f(-(float)i * LOG2_10000_OVER_32);
  float sn, cs;
  sincosf((float)pos[t] * inv, &sn, &cs);
  ct[t * 32 + i] = cs;
  st[t * 32 + i] = sn;
}

// ---------------- plain bf16 MFMA GEMM: C = A @ Bt^T ----------------
// BM=64, BN=128, BK=64, 4 waves (64x32 each), gl16 + T2 swizzle, m97 2-barrier.
template <typename CT>
__global__ __launch_bounds__(256) void gemm_bf16(const short* __restrict__ A,
                                                 const short* __restrict__ Bt,
                                                 CT* __restrict__ C,
                                                 int M, int N, int K) {
  __shared__ short As[64 * 64];
  __shared__ short Bs[128 * 64];
  int flat = blockIdx.x + gridDim.x * blockIdx.y;
  flat = xcd_swz(flat, gridDim.x * gridDim.y);
  const int byg = flat % gridDim.y;            // M fastest: XCD chunk shares B-panels
  const int bxg = flat / gridDim.y;
  const int tid = threadIdx.x;
  const int lane = tid & 63, wv = tid >> 6;
  const int wc = wv * 32;
  const int bm = byg * 64, bn = bxg * 128;
  const int l15 = lane & 15, l4 = lane >> 4;
  const int sx = (l15 & 7) * 8;                // read-side swizzle (shorts)
  f32x4 acc[4][2];
#pragma unroll
  for (int i = 0; i < 4; ++i)
#pragma unroll
    for (int j = 0; j < 2; ++j) acc[i][j] = f32x4{0.f, 0.f, 0.f, 0.f};
  for (int k0 = 0; k0 < K; k0 += 64) {
    __syncthreads();
#pragma unroll
    for (int i = 0; i < 2; ++i) {              // A: 64 rows x 8 chunks
      const int idx = tid + i * 256;
      const int row = idx >> 3, c8 = (idx & 7) * 8;
      const int cs = c8 ^ ((row & 7) * 8);
      gl16(A + (size_t)(bm + row) * K + k0 + cs, &As[idx * 8]);
    }
#pragma unroll
    for (int i = 0; i < 4; ++i) {              // B: 128 rows x 8 chunks
      const int idx = tid + i * 256;
      const int row = idx >> 3, c8 = (idx & 7) * 8;
      const int cs = c8 ^ ((row & 7) * 8);
      gl16(Bt + (size_t)(bn + row) * K + k0 + cs, &Bs[idx * 8]);
    }
    __syncthreads();
    short8 fa[4][2], fb[2][2];
#pragma unroll
    for (int rt = 0; rt < 4; ++rt)
#pragma unroll
      for (int kk = 0; kk < 2; ++kk)
        fa[rt][kk] = *(const short8*)(&As[(rt * 16 + l15) * 64 + ((kk * 32 + l4 * 8) ^ sx)]);
#pragma unroll
    for (int ct = 0; ct < 2; ++ct)
#pragma unroll
      for (int kk = 0; kk < 2; ++kk)
        fb[ct][kk] = *(const short8*)(&Bs[(wc + ct * 16 + l15) * 64 + ((kk * 32 + l4 * 8) ^ sx)]);
#pragma unroll
    for (int kk = 0; kk < 2; ++kk)
#pragma unroll
      for (int rt = 0; rt < 4; ++rt)
#pragma unroll
        for (int ct = 0; ct < 2; ++ct)
          acc[rt][ct] = __builtin_amdgcn_mfma_f32_16x16x32_bf16(fa[rt][kk], fb[ct][kk], acc[rt][ct], 0, 0, 0);
  }
#pragma unroll
  for (int rt = 0; rt < 4; ++rt)
#pragma unroll
    for (int ct = 0; ct < 2; ++ct)
#pragma unroll
      for (int r = 0; r < 4; ++r) {
        const int row = bm + rt * 16 + l4 * 4 + r;
        const int col = bn + wc + ct * 16 + l15;
        const float v = acc[rt][ct][r];
        if constexpr (std::is_same<CT, float>::value) C[(size_t)row * N + col] = v;
        else C[(size_t)row * N + col] = __float2bfloat16(v);
      }
}

// ---------------- q_b GEMM with fused RoPE (table) + [h][q][192] repack ----------------
__global__ __launch_bounds__(256) void gemm_qb(const short* __restrict__ A,
                                               const short* __restrict__ Bt,
                                               const float* __restrict__ ropeC,
                                               const float* __restrict__ ropeS,
                                               short* __restrict__ qhb) {
  const int M = TT, N = 6144, K = QLL;
  __shared__ short As[64 * 64];
  __shared__ short Bs[128 * 64];
  int flat = blockIdx.x + gridDim.x * blockIdx.y;
  flat = xcd_swz(flat, gridDim.x * gridDim.y);
  const int byg = flat % gridDim.y;
  const int bxg = flat / gridDim.y;
  const int tid = threadIdx.x;
  const int lane = tid & 63, wv = tid >> 6;
  const int wc = wv * 32;
  const int bm = byg * 64, bn = bxg * 128;
  const int l15 = lane & 15, l4 = lane >> 4;
  const int sx = (l15 & 7) * 8;
  f32x4 acc[4][2];
#pragma unroll
  for (int i = 0; i < 4; ++i)
#pragma unroll
    for (int j = 0; j < 2; ++j) acc[i][j] = f32x4{0.f, 0.f, 0.f, 0.f};
  for (int k0 = 0; k0 < K; k0 += 64) {
    __syncthreads();
#pragma unroll
    for (int i = 0; i < 2; ++i) {
      const int idx = tid + i * 256;
      const int row = idx >> 3, c8 = (idx & 7) * 8;
      const int cs = c8 ^ ((row & 7) * 8);
      gl16(A + (size_t)(bm + row) * K + k0 + cs, &As[idx * 8]);
    }
#pragma unroll
    for (int i = 0; i < 4; ++i) {
      const int idx = tid + i * 256;
      const int row = idx >> 3, c8 = (idx & 7) * 8;
      const int cs = c8 ^ ((row & 7) * 8);
      gl16(Bt + (size_t)(bn + row) * K + k0 + cs, &Bs[idx * 8]);
    }
    __syncthreads();
    short8 fa[4][2], fb[2][2];
#pragma unroll
    for (int rt = 0; rt < 4; ++rt)
#pragma unroll
      for (int kk = 0; kk < 2; ++kk)
        fa[rt][kk] = *(const short8*)(&As[(rt * 16 + l15) * 64 + ((kk * 32 + l4 * 8) ^ sx)]);
#pragma unroll
    for (int ct = 0; ct < 2; ++ct)
#pragma unroll
      for (int kk = 0; kk < 2; ++kk)
        fb[ct][kk] = *(const short8*)(&Bs[(wc + ct * 16 + l15) * 64 + ((kk * 32 + l4 * 8) ^ sx)]);
#pragma unroll
    for (int kk = 0; kk < 2; ++kk)
#pragma unroll
      for (int rt = 0; rt < 4; ++rt)
#pragma unroll
        for (int ct = 0; ct < 2; ++ct)
          acc[rt][ct] = __builtin_amdgcn_mfma_f32_16x16x32_bf16(fa[rt][kk], fb[ct][kk], acc[rt][ct], 0, 0, 0);
  }
  // epilogue: rope cols d>=128 of each 192-wide head (table), write qhb[h][row][d]
#pragma unroll
  for (int rt = 0; rt < 4; ++rt)
#pragma unroll
    for (int r = 0; r < 4; ++r) {
      const int row = bm + rt * 16 + l4 * 4 + r;
#pragma unroll
      for (int ct = 0; ct < 2; ++ct) {
        const int col = bn + wc + ct * 16 + l15;
        float v = acc[rt][ct][r];
        const float pv = __shfl_xor(v, 1);     // pair partner (col bit0 == lane bit0)
        const int head = col / 192, d = col - head * 192;
        if (d >= 128) {
          const int i = (d - 128) >> 1;
          const float cs = ropeC[row * 32 + i];
          const float sn = ropeS[row * 32 + i];
          v = (col & 1) ? (pv * sn + v * cs) : (v * cs - pv * sn);
        }
        qhb[((size_t)head * 1024 + row) * 192 + d] = f2bf(v);
      }
    }
}

// ---------------- idx_qb GEMM (bf16x3, BK=64, z=1) with fused RoPE + repack + split ----
// N=4096 = 32 idx-heads x 128. Epilogue: rope d<64, write qih_h/qih_l [h][q][128].
__global__ __launch_bounds__(256) void gemm_idx(const short* __restrict__ Ah,
                                                const short* __restrict__ Al,
                                                const short* __restrict__ Bth,
                                                const short* __restrict__ Btl,
                                                const float* __restrict__ ropeC,
                                                const float* __restrict__ ropeS,
                                                short* __restrict__ qih,
                                                short* __restrict__ qil) {
  const int K = QLL;
  __shared__ short AhS[64 * 64], AlS[64 * 64];    // 8 KB + 8 KB
  __shared__ short BhS[128 * 64], BlS[128 * 64];  // 16 KB + 16 KB
  int flat = blockIdx.x + gridDim.x * blockIdx.y;
  flat = xcd_swz(flat, gridDim.x * gridDim.y);
  const int byg = flat % gridDim.y;
  const int bxg = flat / gridDim.y;
  const int tid = threadIdx.x;
  const int lane = tid & 63, wv = tid >> 6;
  const int wc = wv * 32;
  const int bm = byg * 64, bn = bxg * 128;
  const int l15 = lane & 15, l4 = lane >> 4;
  const int sx = (l15 & 7) * 8;
  f32x4 acc[4][2];
#pragma unroll
  for (int i = 0; i < 4; ++i)
#pragma unroll
    for (int j = 0; j < 2; ++j) acc[i][j] = f32x4{0.f, 0.f, 0.f, 0.f};
  for (int k0 = 0; k0 < K; k0 += 64) {
    __syncthreads();
#pragma unroll
    for (int i = 0; i < 2; ++i) {              // A hi + lo: 64 rows x 8 chunks each
      const int idx = tid + i * 256;
      const int row = idx >> 3, c8 = (idx & 7) * 8;
      const int cs = c8 ^ ((row & 7) * 8);
      gl16(Ah + (size_t)(bm + row) * K + k0 + cs, &AhS[idx * 8]);
      gl16(Al + (size_t)(bm + row) * K + k0 + cs, &AlS[idx * 8]);
    }
#pragma unroll
    for (int i = 0; i < 4; ++i) {              // B hi + lo: 128 rows x 8 chunks each
      const int idx = tid + i * 256;
      const int row = idx >> 3, c8 = (idx & 7) * 8;
      const int cs = c8 ^ ((row & 7) * 8);
      gl16(Bth + (size_t)(bn + row) * K + k0 + cs, &BhS[idx * 8]);
      gl16(Btl + (size_t)(bn + row) * K + k0 + cs, &BlS[idx * 8]);
    }
    __syncthreads();
    short8 fah[4][2], fal[4][2], fbh[2][2], fbl[2][2];
#pragma unroll
    for (int rt = 0; rt < 4; ++rt) {
      const int row = rt * 16 + l15;
#pragma unroll
      for (int kk = 0; kk < 2; ++kk) {
        const int cc = (kk * 32 + l4 * 8) ^ sx;
        fah[rt][kk] = *(const short8*)&AhS[row * 64 + cc];
        fal[rt][kk] = *(const short8*)&AlS[row * 64 + cc];
      }
    }
#pragma unroll
    for (int ct = 0; ct < 2; ++ct) {
      const int row = wc + ct * 16 + l15;
#pragma unroll
      for (int kk = 0; kk < 2; ++kk) {
        const int cc = (kk * 32 + l4 * 8) ^ sx;
        fbh[ct][kk] = *(const short8*)&BhS[row * 64 + cc];
        fbl[ct][kk] = *(const short8*)&BlS[row * 64 + cc];
      }
    }
#pragma unroll
    for (int kk = 0; kk < 2; ++kk)
#pragma unroll
      for (int ct = 0; ct < 2; ++ct)
#pragma unroll
        for (int rt = 0; rt < 4; ++rt) {
          acc[rt][ct] = __builtin_amdgcn_mfma_f32_16x16x32_bf16(fah[rt][kk], fbh[ct][kk], acc[rt][ct], 0, 0, 0);
          acc[rt][ct] = __builtin_amdgcn_mfma_f32_16x16x32_bf16(fah[rt][kk], fbl[ct][kk], acc[rt][ct], 0, 0, 0);
          acc[rt][ct] = __builtin_amdgcn_mfma_f32_16x16x32_bf16(fal[rt][kk], fbh[ct][kk], acc[rt][ct], 0, 0, 0);
        }
  }
  // epilogue: rope d<64 (table), hi/lo split, write qih/qil [h][row][d]
#pragma unroll
  for (int rt = 0; rt < 4; ++rt)
#pragma unroll
    for (int r = 0; r < 4; ++r) {
      const int row = bm + rt * 16 + l4 * 4 + r;
#pragma unroll
      for (int ct = 0; ct < 2; ++ct) {
        const int col = bn + wc + ct * 16 + l15;
        float v = acc[rt][ct][r];
        const float pv = __shfl_xor(v, 1);     // pair partner (col bit0 == lane bit0)
        const int head = col >> 7, d = col & 127;
        if (d < 64) {
          const int i = d >> 1;
          const float cs = ropeC[row * 32 + i];
          const float sn = ropeS[row * 32 + i];
          v = (col & 1) ? (pv * sn + v * cs) : (v * cs - pv * sn);
        }
        const size_t off = ((size_t)head * 1024 + row) * 128 + d;
        const short hbits = f2bf(v);
        qih[off] = hbits;
        qil[off] = f2bf(v - bf2f(hbits));
      }
    }
}

// ---------------- kv_b GEMM with fused kf/vt repack + kpe broadcast ----------------
// N=8192 = 32 heads x 256 (128 k_nope | 128 v). Even col-tiles -> kfb (+kpe), odd -> vtb.
__global__ __launch_bounds__(256) void gemm_kvb(const short* __restrict__ A,
                                                const short* __restrict__ Bt,
                                                const short* __restrict__ kpe_bf,
                                                short* __restrict__ kfb,
                                                short* __restrict__ vtb) {
  const int K = KLL;
  __shared__ short As[64 * 64];
  __shared__ short Bs[128 * 64];
  __shared__ short tr[128 * 66];
  int flat = blockIdx.x + gridDim.x * blockIdx.y;
  flat = xcd_swz(flat, gridDim.x * gridDim.y);
  const int byg = flat % gridDim.y;
  const int bxg = flat / gridDim.y;
  const int tid = threadIdx.x;
  const int lane = tid & 63, wv = tid >> 6;
  const int wc = wv * 32;
  const int bm = byg * 64, bn = bxg * 128;
  const int l15 = lane & 15, l4 = lane >> 4;
  const int sx = (l15 & 7) * 8;
  f32x4 acc[4][2];
#pragma unroll
  for (int i = 0; i < 4; ++i)
#pragma unroll
    for (int j = 0; j < 2; ++j) acc[i][j] = f32x4{0.f, 0.f, 0.f, 0.f};
  for (int k0 = 0; k0 < K; k0 += 64) {
    __syncthreads();
#pragma unroll
    for (int i = 0; i < 2; ++i) {
      const int idx = tid + i * 256;
      const int row = idx >> 3, c8 = (idx & 7) * 8;
      const int cs = c8 ^ ((row & 7) * 8);
      gl16(A + (size_t)(bm + row) * K + k0 + cs, &As[idx * 8]);
    }
#pragma unroll
    for (int i = 0; i < 4; ++i) {
      const int idx = tid + i * 256;
      const int row = idx >> 3, c8 = (idx & 7) * 8;
      const int cs = c8 ^ ((row & 7) * 8);
      gl16(Bt + (size_t)(bn + row) * K + k0 + cs, &Bs[idx * 8]);
    }
    __syncthreads();
    short8 fa[4][2], fb[2][2];
#pragma unroll
    for (int rt = 0; rt < 4; ++rt)
#pragma unroll
      for (int kk = 0; kk < 2; ++kk)
        fa[rt][kk] = *(const short8*)(&As[(rt * 16 + l15) * 64 + ((kk * 32 + l4 * 8) ^ sx)]);
#pragma unroll
    for (int ct = 0; ct < 2; ++ct)
#pragma unroll
      for (int kk = 0; kk < 2; ++kk)
        fb[ct][kk] = *(const short8*)(&Bs[(wc + ct * 16 + l15) * 64 + ((kk * 32 + l4 * 8) ^ sx)]);
#pragma unroll
    for (int kk = 0; kk < 2; ++kk)
#pragma unroll
      for (int rt = 0; rt < 4; ++rt)
#pragma unroll
        for (int ct = 0; ct < 2; ++ct)
          acc[rt][ct] = __builtin_amdgcn_mfma_f32_16x16x32_bf16(fa[rt][kk], fb[ct][kk], acc[rt][ct], 0, 0, 0);
  }
  const int h = bn >> 8;
  const bool isv = (bn >> 7) & 1;
  if (!isv) {
    // k_nope: kfb[h][row][d], d = wc+ct*16+l15 in 0..127
#pragma unroll
    for (int rt = 0; rt < 4; ++rt)
#pragma unroll
      for (int ct = 0; ct < 2; ++ct)
#pragma unroll
        for (int r = 0; r < 4; ++r) {
          const int row = bm + rt * 16 + l4 * 4 + r;
          const int d = wc + ct * 16 + l15;
          kfb[((size_t)h * 1024 + row) * 192 + d] = f2bf(acc[rt][ct][r]);
        }
    // kpe broadcast: rows bm..bm+63, cols 128..191
#pragma unroll
    for (int i = 0; i < 2; ++i) {
      const int idx = tid + i * 256;         // 512 chunks = 64 rows x 8 chunks
      const int row = idx >> 3, c = idx & 7;
      *(short8*)(kfb + ((size_t)h * 1024 + bm + row) * 192 + 128 + c * 8) =
          *(const short8*)(kpe_bf + (size_t)(bm + row) * 64 + c * 8);
    }
  } else {
    // v: LDS transpose then vtb[h][d][k] coalesced along k
    __syncthreads();
#pragma unroll
    for (int rt = 0; rt < 4; ++rt)
#pragma unroll
      for (int ct = 0; ct < 2; ++ct)
#pragma unroll
        for (int r = 0; r < 4; ++r)
          tr[(wc + ct * 16 + l15) * 66 + rt * 16 + l4 * 4 + r] = f2bf(acc[rt][ct][r]);
    __syncthreads();
    const int d = tid >> 1, half = tid & 1;
    short* dst = vtb + ((size_t)h * 128 + d) * 1024 + bm + half * 32;
#pragma unroll
    for (int c = 0; c < 4; ++c) {
      short8 o;
#pragma unroll
      for (int e = 0; e < 8; ++e) o[e] = tr[d * 66 + half * 32 + c * 8 + e];
      *(short8*)(dst + c * 8) = o;
    }
  }
}

// ---------------- plain bf16 split-K GEMM -> fp32 partials ----------
__global__ __launch_bounds__(256) void gemm1_splitk(const short* __restrict__ A,
                                                    const short* __restrict__ Bt,
                                                    float* __restrict__ part,
                                                    int M, int Np, int K, int kchunk) {
  __shared__ short As[64 * 64];
  __shared__ short Bs[128 * 64];
  int flat = blockIdx.x + gridDim.x * (blockIdx.y + gridDim.y * blockIdx.z);
  flat = xcd_swz(flat, gridDim.x * gridDim.y * gridDim.z);
  const int byg = flat % gridDim.y;
  int tmp = flat / gridDim.y;
  const int bxg = tmp % gridDim.x, bzg = tmp / gridDim.x;
  const int tid = threadIdx.x;
  const int lane = tid & 63, wv = tid >> 6;
  const int wc = wv * 32;
  const int bm = byg * 64, bn = bxg * 128;
  const int kbeg = bzg * kchunk;
  const int l15 = lane & 15, l4 = lane >> 4;
  const int sx = (l15 & 7) * 8;
  f32x4 acc[4][2];
#pragma unroll
  for (int i = 0; i < 4; ++i)
#pragma unroll
    for (int j = 0; j < 2; ++j) acc[i][j] = f32x4{0.f, 0.f, 0.f, 0.f};
  for (int k0 = kbeg; k0 < kbeg + kchunk; k0 += 64) {
    __syncthreads();
#pragma unroll
    for (int i = 0; i < 2; ++i) {
      const int idx = tid + i * 256;
      const int row = idx >> 3, c8 = (idx & 7) * 8;
      const int cs = c8 ^ ((row & 7) * 8);
      gl16(A + (size_t)(bm + row) * K + k0 + cs, &As[idx * 8]);
    }
#pragma unroll
    for (int i = 0; i < 4; ++i) {
      const int idx = tid + i * 256;
      const int row = idx >> 3, c8 = (idx & 7) * 8;
      const int cs = c8 ^ ((row & 7) * 8);
      gl16(Bt + (size_t)(bn + row) * K + k0 + cs, &Bs[idx * 8]);
    }
    __syncthreads();
    short8 fa[4][2], fb[2][2];
#pragma unroll
    for (int rt = 0; rt < 4; ++rt)
#pragma unroll
      for (int kk = 0; kk < 2; ++kk)
        fa[rt][kk] = *(const short8*)(&As[(rt * 16 + l15) * 64 + ((kk * 32 + l4 * 8) ^ sx)]);
#pragma unroll
    for (int ct = 0; ct < 2; ++ct)
#pragma unroll
      for (int kk = 0; kk < 2; ++kk)
        fb[ct][kk] = *(const short8*)(&Bs[(wc + ct * 16 + l15) * 64 + ((kk * 32 + l4 * 8) ^ sx)]);
#pragma unroll
    for (int kk = 0; kk < 2; ++kk)
#pragma unroll
      for (int rt = 0; rt < 4; ++rt)
#pragma unroll
        for (int ct = 0; ct < 2; ++ct)
          acc[rt][ct] = __builtin_amdgcn_mfma_f32_16x16x32_bf16(fa[rt][kk], fb[ct][kk], acc[rt][ct], 0, 0, 0);
  }
  float* dst = part + (size_t)bzg * M * Np;
#pragma unroll
  for (int rt = 0; rt < 4; ++rt)
#pragma unroll
    for (int ct = 0; ct < 2; ++ct)
#pragma unroll
      for (int r = 0; r < 4; ++r)
        dst[(size_t)(bm + rt * 16 + l4 * 4 + r) * Np + bn + wc + ct * 16 + l15] =
            acc[rt][ct][r];
}

// ---------------- deterministic split-K reduce -> fp32 C ----------------
__global__ __launch_bounds__(256) void reduce_splitk(const float* __restrict__ part,
                                                     float* __restrict__ C,
                                                     int M, int Np, int ksplit) {
  const int c = blockIdx.x * 256 + threadIdx.x;
  const int m = blockIdx.y;
  float s = 0.f;
  for (int z = 0; z < ksplit; ++z) s += part[((size_t)z * M + m) * Np + c];
  C[(size_t)m * Np + c] = s;
}

// ---------------- pre-split bf16x3 GEMM, optional split-K ----------------
// BM=64, BK=32, hi/lo fused in [.][64] rows (cols 0-31 hi, 32-63 lo); T2 swizzle.
__global__ __launch_bounds__(256) void gemm3(const short* __restrict__ Ah,
                                             const short* __restrict__ Al,
                                             const short* __restrict__ Bth,
                                             const short* __restrict__ Btl,
                                             float* __restrict__ part,
                                             int M, int Np, int K, int kchunk) {
  __shared__ short AS[64 * 64], BS[128 * 64];
  int flat = blockIdx.x + gridDim.x * (blockIdx.y + gridDim.y * blockIdx.z);
  flat = xcd_swz(flat, gridDim.x * gridDim.y * gridDim.z);
  const int byg = flat % gridDim.y;
  int tmp = flat / gridDim.y;
  const int bxg = tmp % gridDim.x, bzg = tmp / gridDim.x;
  const int tid = threadIdx.x;
  const int lane = tid & 63, wv = tid >> 6;
  const int wc = wv * 32;
  const int l15 = lane & 15, l4 = lane >> 4;
  const int sx = (l15 & 7) * 8;
  const int bm = byg * 64, bn = bxg * 128;
  const int kbeg = bzg * kchunk;
  f32x4 acc[4][2];
#pragma unroll
  for (int i = 0; i < 4; ++i)
#pragma unroll
    for (int j = 0; j < 2; ++j) acc[i][j] = f32x4{0.f, 0.f, 0.f, 0.f};
  for (int k0 = kbeg; k0 < kbeg + kchunk; k0 += 32) {
    __syncthreads();
#pragma unroll
    for (int i = 0; i < 2; ++i) {              // A fused: 64 rows x 8 chunks
      const int idx = tid + i * 256;
      const int row = idx >> 3, c8 = (idx & 7) * 8;
      const int cs = c8 ^ ((row & 7) * 8);     // logical fused col
      const short* srcA = (cs < 32) ? (Ah + (size_t)(bm + row) * K + k0 + cs)
                                    : (Al + (size_t)(bm + row) * K + k0 + (cs - 32));
      gl16(srcA, &AS[idx * 8]);
    }
#pragma unroll
    for (int i = 0; i < 4; ++i) {              // B fused: 128 rows x 8 chunks
      const int idx = tid + i * 256;
      const int row = idx >> 3, c8 = (idx & 7) * 8;
      const int cs = c8 ^ ((row & 7) * 8);
      const short* srcB = (cs < 32) ? (Bth + (size_t)(bn + row) * K + k0 + cs)
                                    : (Btl + (size_t)(bn + row) * K + k0 + (cs - 32));
      gl16(srcB, &BS[idx * 8]);
    }
    __syncthreads();
    short8 fah[4], fal[4], fbh[2], fbl[2];
#pragma unroll
    for (int rt = 0; rt < 4; ++rt) {
      const int row = rt * 16 + l15;
      fah[rt] = *(const short8*)&AS[row * 64 + ((l4 * 8) ^ sx)];
      fal[rt] = *(const short8*)&AS[row * 64 + ((32 + l4 * 8) ^ sx)];
    }
#pragma unroll
    for (int ct = 0; ct < 2; ++ct) {
      const int row = wc + ct * 16 + l15;
      fbh[ct] = *(const short8*)&BS[row * 64 + ((l4 * 8) ^ sx)];
      fbl[ct] = *(const short8*)&BS[row * 64 + ((32 + l4 * 8) ^ sx)];
    }
#pragma unroll
    for (int ct = 0; ct < 2; ++ct)
#pragma unroll
      for (int rt = 0; rt < 4; ++rt) {
        acc[rt][ct] = __builtin_amdgcn_mfma_f32_16x16x32_bf16(fah[rt], fbh[ct], acc[rt][ct], 0, 0, 0);
        acc[rt][ct] = __builtin_amdgcn_mfma_f32_16x16x32_bf16(fah[rt], fbl[ct], acc[rt][ct], 0, 0, 0);
        acc[rt][ct] = __builtin_amdgcn_mfma_f32_16x16x32_bf16(fal[rt], fbh[ct], acc[rt][ct], 0, 0, 0);
      }
  }
  float* dst = part + (size_t)bzg * M * Np;
#pragma unroll
  for (int rt = 0; rt < 4; ++rt)
#pragma unroll
    for (int ct = 0; ct < 2; ++ct)
#pragma unroll
      for (int r = 0; r < 4; ++r)
        dst[(size_t)(bm + rt * 16 + l4 * 4 + r) * Np + bn + wc + ct * 16 + l15] =
            acc[rt][ct][r];
}

// ---------------- fused qkv epilogue: split-K reduce + 2x RMS + kpe rope -> bf16 ------
__global__ __launch_bounds__(256) void qkv_post(const float* __restrict__ qpart,
                                                const float* __restrict__ tpart,
                                                const float* __restrict__ q_ln_w,
                                                const float* __restrict__ kv_ln_w,
                                                const float* __restrict__ ropeC,
                                                const float* __restrict__ ropeS,
                                                short* __restrict__ qcn_bf,
                                                short* __restrict__ qcn_lo,
                                                short* __restrict__ kvn_bf,
                                                short* __restrict__ kpe_bf) {
  const int t = blockIdx.x, tid = threadIdx.x;
  __shared__ float red[4];
  float qv[6];
  float ss = 0.f;
#pragma unroll
  for (int j = 0; j < 6; ++j) {
    const int c = tid + j * 256;
    float s = 0.f;
#pragma unroll
    for (int z = 0; z < 4; ++z) s += qpart[((size_t)z * TT + t) * QLL + c];
    qv[j] = s;
    ss = fmaf(s, s, ss);
  }
#pragma unroll
  for (int o = 32; o > 0; o >>= 1) ss += __shfl_xor(ss, o);
  if ((tid & 63) == 0) red[tid >> 6] = ss;
  __syncthreads();
  const float rq = rsqrtf((red[0] + red[1] + red[2] + red[3]) / (float)QLL + 1e-6f);
  __syncthreads();
#pragma unroll
  for (int j = 0; j < 6; ++j) {
    const int c = tid + j * 256;
    const float v = qv[j] * rq * q_ln_w[c];
    const short h = f2bf(v);
    qcn_bf[(size_t)t * QLL + c] = h;
    qcn_lo[(size_t)t * QLL + c] = f2bf(v - bf2f(h));
  }
  float kv2[2];
  float ss2 = 0.f;
#pragma unroll
  for (int j = 0; j < 2; ++j) {
    const int c = tid + j * 256;
    float s = 0.f;
#pragma unroll
    for (int z = 0; z < 4; ++z) s += tpart[((size_t)z * TT + t) * 640 + c];
    kv2[j] = s;
    ss2 = fmaf(s, s, ss2);
  }
#pragma unroll
  for (int o = 32; o > 0; o >>= 1) ss2 += __shfl_xor(ss2, o);
  if ((tid & 63) == 0) red[tid >> 6] = ss2;
  __syncthreads();
  const float rkv = rsqrtf((red[0] + red[1] + red[2] + red[3]) / (float)KLL + 1e-6f);
#pragma unroll
  for (int j = 0; j < 2; ++j) {
    const int c = tid + j * 256;
    kvn_bf[(size_t)t * KLL + c] = f2bf(kv2[j] * rkv * kv_ln_w[c]);
  }
  if (tid < 32) {
    float x1 = 0.f, x2 = 0.f;
#pragma unroll
    for (int z = 0; z < 4; ++z) {
      x1 += tpart[((size_t)z * TT + t) * 640 + 512 + 2 * tid];
      x2 += tpart[((size_t)z * TT + t) * 640 + 512 + 2 * tid + 1];
    }
    const float cs = ropeC[t * 32 + tid];
    const float sn = ropeS[t * 32 + tid];
    kpe_bf[(size_t)t * 64 + 2 * tid]     = f2bf(x1 * cs - x2 * sn);
    kpe_bf[(size_t)t * 64 + 2 * tid + 1] = f2bf(x1 * sn + x2 * cs);
  }
}

// ---------------- fused ki epilogue: z-sum + LN + RoPE + hi/lo split + wtsb -----------
__global__ __launch_bounds__(256) void ki_prep2(const float* __restrict__ part,
                                                const float* __restrict__ w,
                                                const float* __restrict__ b,
                                                const float* __restrict__ ropeC,
                                                const float* __restrict__ ropeS,
                                                short* __restrict__ kih,
                                                short* __restrict__ kil,
                                                float* __restrict__ wtsb) {
  const int t = blockIdx.x, tid = threadIdx.x;
  __shared__ float red[4], red2[4];
  float s = 0.f;
#pragma unroll
  for (int z = 0; z < 8; ++z) s += part[((size_t)z * TT + t) * 256 + tid];
  if (tid >= 128 && tid < 160) wtsb[(size_t)t * 32 + (tid - 128)] = s;
  const float v = (tid < 128) ? s : 0.f;
  float sm = v;
#pragma unroll
  for (int o = 32; o > 0; o >>= 1) sm += __shfl_xor(sm, o);
  if ((tid & 63) == 0) red[tid >> 6] = sm;
  __syncthreads();
  const float m = (red[0] + red[1]) * (1.f / 128.f);
  const float dv = v - m;
  float sq = (tid < 128) ? dv * dv : 0.f;
#pragma unroll
  for (int o = 32; o > 0; o >>= 1) sq += __shfl_xor(sq, o);
  if ((tid & 63) == 0) red2[tid >> 6] = sq;
  __syncthreads();
  const float var = (red2[0] + red2[1]) * (1.f / 128.f);
  if (tid < 128) {
    float x = dv * rsqrtf(var + 1e-6f) * w[tid] + b[tid];
    if (tid < 64) {
      const float part2 = __shfl_xor(x, 1);
      const int pi = tid >> 1;
      const float cs = ropeC[t * 32 + pi];
      const float sn = ropeS[t * 32 + pi];
      x = (tid & 1) ? (part2 * sn + x * cs) : (x * cs - part2 * sn);
    }
    const short h = f2bf(x);
    kih[(size_t)t * 128 + tid] = h;
    kil[(size_t)t * 128 + tid] = f2bf(x - bf2f(h));
  }
}

// ---------------- f32 -> bf16 hi/lo split (flat) ----------------
__global__ __launch_bounds__(256) void split_cast(const float* __restrict__ in,
                                                  short* __restrict__ hi,
                                                  short* __restrict__ lo, int n4) {
  const int i = blockIdx.x * 256 + threadIdx.x;
  if (i >= n4) return;
  float4 v = *(const float4*)(in + (size_t)i * 4);
  float av[4] = {v.x, v.y, v.z, v.w};
  short4v h, l;
#pragma unroll
  for (int e = 0; e < 4; ++e) {
    h[e] = f2bf(av[e]);
    l[e] = f2bf(av[e] - bf2f(h[e]));
  }
  *(short4v*)(hi + (size_t)i * 4) = h;
  *(short4v*)(lo + (size_t)i * 4) = l;
}

// ---------------- generalized transpose+cast: Bt[n][k] = bf16(B[k][col0+n]) ----------
__global__ __launch_bounds__(256) void transpose_cast_g(const float* __restrict__ B,
                                                        short* __restrict__ Bt,
                                                        int K, int ldB, int col0, int Ncols) {
  __shared__ float tile[64][65];
  const int tid = threadIdx.x;
  const int k0 = blockIdx.y * 64, n0 = blockIdx.x * 64;
  const int nl = tid >> 3, kc = (tid & 7) * 8;
  if (n0 >= Ncols) {
    short8 z = {0, 0, 0, 0, 0, 0, 0, 0};
#pragma unroll
    for (int i = 0; i < 2; ++i) {
      const int n = nl + i * 32;
      *(short8*)(Bt + (size_t)(n0 + n) * K + k0 + kc) = z;
    }
    return;
  }
  const int r = tid >> 4, c4 = (tid & 15) * 4;
#pragma unroll
  for (int i = 0; i < 4; ++i) {
    float4 v = *(const float4*)(B + (size_t)(k0 + r + i * 16) * ldB + col0 + n0 + c4);
    tile[r + i * 16][c4 + 0] = v.x;
    tile[r + i * 16][c4 + 1] = v.y;
    tile[r + i * 16][c4 + 2] = v.z;
    tile[r + i * 16][c4 + 3] = v.w;
  }
  __syncthreads();
#pragma unroll
  for (int i = 0; i < 2; ++i) {
    const int n = nl + i * 32;
    short8 o;
#pragma unroll
    for (int e = 0; e < 8; ++e) o[e] = f2bf(tile[kc + e][n]);
    *(short8*)(Bt + (size_t)(n0 + n) * K + k0 + kc) = o;
  }
}

// ---------------- generalized transpose + hi/lo split cast (partial-tile safe) -------
__global__ __launch_bounds__(256) void transpose_split_cast(const float* __restrict__ B,
                                                            short* __restrict__ Bth,
                                                            short* __restrict__ Btl,
                                                            int K, int ldB, int col0,
                                                            int Ncols) {
  __shared__ float tile[64][65];
  const int tid = threadIdx.x;
  const int k0 = blockIdx.y * 64, n0 = blockIdx.x * 64;
  const int nl = tid >> 3, kc = (tid & 7) * 8;
  if (n0 >= Ncols) {
    short8 z = {0, 0, 0, 0, 0, 0, 0, 0};
#pragma unroll
    for (int i = 0; i < 2; ++i) {
      const int n = nl + i * 32;
      *(short8*)(Bth + (size_t)(n0 + n) * K + k0 + kc) = z;
      *(short8*)(Btl + (size_t)(n0 + n) * K + k0 + kc) = z;
    }
    return;
  }
  const int r = tid >> 4, c4 = (tid & 15) * 4;
#pragma unroll
  for (int i = 0; i < 4; ++i) {
    float4 v = make_float4(0.f, 0.f, 0.f, 0.f);
    if (n0 + c4 < Ncols)
      v = *(const float4*)(B + (size_t)(k0 + r + i * 16) * ldB + col0 + n0 + c4);
    tile[r + i * 16][c4 + 0] = v.x;
    tile[r + i * 16][c4 + 1] = v.y;
    tile[r + i * 16][c4 + 2] = v.z;
    tile[r + i * 16][c4 + 3] = v.w;
  }
  __syncthreads();
#pragma unroll
  for (int i = 0; i < 2; ++i) {
    const int n = nl + i * 32;
    short8 oh, ol;
#pragma unroll
    for (int e = 0; e < 8; ++e) {
      const float x = tile[kc + e][n];
      oh[e] = f2bf(x);
      ol[e] = f2bf(x - bf2f(oh[e]));
    }
    *(short8*)(Bth + (size_t)(n0 + n) * K + k0 + kc) = oh;
    *(short8*)(Btl + (size_t)(n0 + n) * K + k0 + kc) = ol;
  }
}

// ---------------- MFMA indexer logits: triangular grid + XCD swizzle, 8 heads/plane ----
__global__ __launch_bounds__(256) void logits_mfma(const short* __restrict__ qih,
                                                   const short* __restrict__ qil,
                                                   const short* __restrict__ kih_g,
                                                   const short* __restrict__ kil_g,
                                                   const float* __restrict__ wts,
                                                   float* __restrict__ part) {
  const int bid = xcd_swz(blockIdx.x, gridDim.x);
  int bq = (int)((sqrtf(8.f * bid + 1.f) - 1.f) * 0.5f);
  while ((bq + 1) * (bq + 2) / 2 <= bid) ++bq;
  while (bq * (bq + 1) / 2 > bid) --bq;
  const int bk = bid - bq * (bq + 1) / 2;
  const int g = blockIdx.y;  // 0..3 (8 heads each)
  __shared__ short kih[64 * 128], kil[64 * 128];
  __shared__ float swts[64][8];
  const int tid = threadIdx.x;
  const int lane = tid & 63, wv = tid >> 6;
  const int wr = (wv >> 1) * 32, wc = (wv & 1) * 32;
  const int l15 = lane & 15, l4 = lane >> 4;
  const int q0 = bq * 64, k0 = bk * 64;
  {
    const int r0 = tid >> 4;
    const int c8 = (tid & 15) * 8;
#pragma unroll
    for (int i = 0; i < 4; ++i) {
      const int row = r0 + i * 16;
      gl16(kih_g + (size_t)(k0 + row) * 128 + c8, &kih[(tid + i * 256) * 8]);
      gl16(kil_g + (size_t)(k0 + row) * 128 + c8, &kil[(tid + i * 256) * 8]);
    }
  }
#pragma unroll
  for (int i = 0; i < 2; ++i) {
    const int idx = tid + i * 256;
    swts[idx >> 3][idx & 7] = wts[(size_t)(q0 + (idx >> 3)) * 32 + g * 8 + (idx & 7)];
  }
  __syncthreads();
  short8 kbh[2][4], kbl[2][4];
#pragma unroll
  for (int ct = 0; ct < 2; ++ct)
#pragma unroll
    for (int ks = 0; ks < 4; ++ks) {
      kbh[ct][ks] = *(const short8*)&kih[(wc + ct * 16 + l15) * 128 + ks * 32 + l4 * 8];
      kbl[ct][ks] = *(const short8*)&kil[(wc + ct * 16 + l15) * 128 + ks * 32 + l4 * 8];
    }
  f32x4 lacc[2][2];
#pragma unroll
  for (int i = 0; i < 2; ++i)
#pragma unroll
    for (int j = 0; j < 2; ++j) lacc[i][j] = f32x4{0.f, 0.f, 0.f, 0.f};
  for (int hh = 0; hh < 8; ++hh) {
    const int h = g * 8 + hh;
    short8 qah[2][4], qal[2][4];
#pragma unroll
    for (int rt = 0; rt < 2; ++rt)
#pragma unroll
      for (int ks = 0; ks < 4; ++ks) {
        const size_t off = ((size_t)h * 1024 + q0 + wr + rt * 16 + l15) * 128 + ks * 32 + l4 * 8;
        qah[rt][ks] = *(const short8*)(qih + off);
        qal[rt][ks] = *(const short8*)(qil + off);
      }
    f32x4 hacc[2][2];
#pragma unroll
    for (int i = 0; i < 2; ++i)
#pragma unroll
      for (int j = 0; j < 2; ++j) hacc[i][j] = f32x4{0.f, 0.f, 0.f, 0.f};
    __builtin_amdgcn_s_setprio(1);
#pragma unroll
    for (int ks = 0; ks < 4; ++ks)
#pragma unroll
      for (int rt = 0; rt < 2; ++rt)
#pragma unroll
        for (int ct = 0; ct < 2; ++ct) {
          hacc[rt][ct] = __builtin_amdgcn_mfma_f32_16x16x32_bf16(qah[rt][ks], kbh[ct][ks], hacc[rt][ct], 0, 0, 0);
          hacc[rt][ct] = __builtin_amdgcn_mfma_f32_16x16x32_bf16(qah[rt][ks], kbl[ct][ks], hacc[rt][ct], 0, 0, 0);
          hacc[rt][ct] = __builtin_amdgcn_mfma_f32_16x16x32_bf16(qal[rt][ks], kbh[ct][ks], hacc[rt][ct], 0, 0, 0);
        }
    __builtin_amdgcn_s_setprio(0);
#pragma unroll
    for (int rt = 0; rt < 2; ++rt)
#pragma unroll
      for (int ct = 0; ct < 2; ++ct)
#pragma unroll
        for (int r = 0; r < 4; ++r) {
          const int row = wr + rt * 16 + l4 * 4 + r;
          const float w = swts[row][hh] * kWtsScale;
          lacc[rt][ct][r] = fmaf(w, fmaxf(hacc[rt][ct][r], 0.f), lacc[rt][ct][r]);
        }
  }
#pragma unroll
  for (int rt = 0; rt < 2; ++rt)
#pragma unroll
    for (int ct = 0; ct < 2; ++ct)
#pragma unroll
      for (int r = 0; r < 4; ++r)
        part[(size_t)g * TT * TT + (size_t)(q0 + wr + rt * 16 + l4 * 4 + r) * TT +
             (k0 + wc + ct * 16 + l15)] = lacc[rt][ct][r];
}

// ---------------- top-512 -> bitmask: ballot-based, one wave per q-row (4 planes) ------
__global__ __launch_bounds__(256) void topk_mask(const float* __restrict__ part,
                                                 unsigned* __restrict__ maskbuf) {
  const int w = threadIdx.x >> 6;
  const int lane = threadIdx.x & 63;
  const int q = blockIdx.x * 4 + w;
  const size_t NN = (size_t)TT * TT;
  __shared__ unsigned long long bl[4][16];
  unsigned v[16];
#pragma unroll
  for (int j = 0; j < 16; ++j) {
    const int k = j * 64 + lane;
    unsigned uv = 0u;
    if (k <= q) {
      const size_t o = (size_t)q * TT + k;
      const float s = part[o] + part[NN + o] + part[2 * NN + o] + part[3 * NN + o];
      unsigned bb = __float_as_uint(s);
      uv = (bb & 0x80000000u) ? ~bb : (bb | 0x80000000u);
    }
    v[j] = uv;
  }
  if (q + 1 <= TOPKK) {
#pragma unroll
    for (int j = 0; j < 16; ++j) {
      const unsigned long long m = __ballot(j * 64 + lane <= q);
      if (lane == 0) bl[w][j] = m;
    }
  } else {
    unsigned lo = 1u, hi = 0xFFFFFFFFu;
    while (lo < hi) {
      const unsigned mid = lo + ((hi - lo) >> 1) + ((hi - lo) & 1u);
      int c = 0;
#pragma unroll
      for (int j = 0; j < 16; ++j) c += __popcll(__ballot(v[j] >= mid));
      if (c >= TOPKK) lo = mid; else hi = mid - 1u;
    }
    const unsigned ustar = lo;
    int nGreater = 0;
#pragma unroll
    for (int j = 0; j < 16; ++j) nGreater += __popcll(__ballot(v[j] > ustar));
    int need = TOPKK - nGreater;
    const unsigned long long lanemask = lane ? (~0ull >> (64 - lane)) : 0ull;
#pragma unroll
    for (int j = 0; j < 16; ++j) {
      const unsigned long long bg = __ballot(v[j] > ustar);
      const unsigned long long be = __ballot(v[j] == ustar);
      const int ce = __popcll(be);
      const int take = need < ce ? need : ce;
      const int rank = __popcll(be & lanemask);
      const bool selme = ((be >> lane) & 1ull) && (rank < take);
      const unsigned long long m = bg | __ballot(selme);
      if (lane == 0) bl[w][j] = m;
      need -= take;
    }
  }
  __builtin_amdgcn_s_waitcnt(0);
  if (lane < 32)
    maskbuf[(size_t)q * 32 + lane] = (unsigned)(bl[w][lane >> 1] >> ((lane & 1) * 32));
}

// ---------------- masked dense MFMA attention ----------------
__global__ __launch_bounds__(256) void attn_mfma(const short* __restrict__ qh,
                                                 const short* __restrict__ kf,
                                                 const short* __restrict__ vt,
                                                 const unsigned* __restrict__ maskbuf,
                                                 short* __restrict__ ao) {
  const int h = blockIdx.x;
  const int yy = blockIdx.y;
  const int qt = (yy < 8) ? (yy * 2) : (31 - yy * 2);
  const int tid = threadIdx.x;
  const int lane = tid & 63, w = tid >> 6;
  const int l15 = lane & 15, l4 = lane >> 4;
  const int q0 = qt * 64;
  __shared__ short kfs[64 * 200];
  __shared__ short vts[128 * 72];
  __shared__ short ps[4][16][72];
  __shared__ unsigned m32s[64][2];
  short8 qf[6];
#pragma unroll
  for (int ks = 0; ks < 6; ++ks)
    qf[ks] = *(const short8*)(qh + ((size_t)h * 1024 + q0 + w * 16 + l15) * 192 + ks * 32 + l4 * 8);
  f32x4 of[8];
#pragma unroll
  for (int dt = 0; dt < 8; ++dt) of[dt] = f32x4{0.f, 0.f, 0.f, 0.f};
  float m[4], l[4];
#pragma unroll
  for (int r = 0; r < 4; ++r) { m[r] = -INFINITY; l[r] = 0.f; }

  for (int kt = 0; kt <= qt; ++kt) {
    const int k0 = kt * 64;
    __syncthreads();
#pragma unroll
    for (int i = 0; i < 6; ++i) {
      const int idx = tid + i * 256;
      const int row = idx / 24, c = idx - row * 24;
      *(short8*)&kfs[row * 200 + c * 8] =
          *(const short8*)(kf + ((size_t)h * 1024 + k0 + row) * 192 + c * 8);
    }
#pragma unroll
    for (int i = 0; i < 4; ++i) {
      const int idx = tid + i * 256;
      const int row = idx >> 3, c = idx & 7;
      *(short8*)&vts[row * 72 + c * 8] =
          *(const short8*)(vt + ((size_t)h * 128 + row) * 1024 + k0 + c * 8);
    }
    if (tid < 128)
      m32s[tid >> 1][tid & 1] = maskbuf[(size_t)(q0 + (tid >> 1)) * 32 + (k0 >> 5) + (tid & 1)];
    __syncthreads();
    f32x4 sacc[4];
#pragma unroll
    for (int j = 0; j < 4; ++j) sacc[j] = f32x4{0.f, 0.f, 0.f, 0.f};
    __builtin_amdgcn_s_setprio(1);
#pragma unroll
    for (int ks = 0; ks < 6; ++ks)
#pragma unroll
      for (int j = 0; j < 4; ++j) {
        short8 kb = *(const short8*)&kfs[(j * 16 + l15) * 200 + ks * 32 + l4 * 8];
        sacc[j] = __builtin_amdgcn_mfma_f32_16x16x32_bf16(qf[ks], kb, sacc[j], 0, 0, 0);
      }
    __builtin_amdgcn_s_setprio(0);
    float tmax[4] = {-INFINITY, -INFINITY, -INFINITY, -INFINITY};
#pragma unroll
    for (int j = 0; j < 4; ++j)
#pragma unroll
      for (int r = 0; r < 4; ++r) {
        const int kcol = j * 16 + l15;
        const unsigned um = m32s[w * 16 + l4 * 4 + r][kcol >> 5];
        float s = sacc[j][r] * kScaling;
        s = ((um >> (kcol & 31)) & 1u) ? s : -INFINITY;
        sacc[j][r] = s;
        tmax[r] = fmaxf(tmax[r], s);
      }
#pragma unroll
    for (int r = 0; r < 4; ++r) {
      tmax[r] = fmaxf(tmax[r], __shfl_xor(tmax[r], 1));
      tmax[r] = fmaxf(tmax[r], __shfl_xor(tmax[r], 2));
      tmax[r] = fmaxf(tmax[r], __shfl_xor(tmax[r], 4));
      tmax[r] = fmaxf(tmax[r], __shfl_xor(tmax[r], 8));
    }
    float f[4];
#pragma unroll
    for (int r = 0; r < 4; ++r) {
      const float mn = fmaxf(m[r], tmax[r]);
      f[r] = __expf(fmaxf(m[r], -1e30f) - fmaxf(mn, -1e30f));
      m[r] = mn;
      l[r] *= f[r];
    }
    float psum[4] = {0.f, 0.f, 0.f, 0.f};
#pragma unroll
    for (int j = 0; j < 4; ++j)
#pragma unroll
      for (int r = 0; r < 4; ++r) {
        const float p = __expf(sacc[j][r] - fmaxf(m[r], -1e30f));
        psum[r] += p;
        ps[w][l4 * 4 + r][j * 16 + l15] = f2bf(p);
      }
#pragma unroll
    for (int r = 0; r < 4; ++r) {
      psum[r] += __shfl_xor(psum[r], 1);
      psum[r] += __shfl_xor(psum[r], 2);
      psum[r] += __shfl_xor(psum[r], 4);
      psum[r] += __shfl_xor(psum[r], 8);
      l[r] += psum[r];
    }
#pragma unroll
    for (int dt = 0; dt < 8; ++dt)
#pragma unroll
      for (int r = 0; r < 4; ++r) of[dt][r] *= f[r];
    short8 pa0 = *(const short8*)&ps[w][l15][l4 * 8];
    short8 pa1 = *(const short8*)&ps[w][l15][32 + l4 * 8];
    __builtin_amdgcn_s_setprio(1);
#pragma unroll
    for (int dt = 0; dt < 8; ++dt) {
      short8 vb0 = *(const short8*)&vts[(dt * 16 + l15) * 72 + l4 * 8];
      short8 vb1 = *(const short8*)&vts[(dt * 16 + l15) * 72 + 32 + l4 * 8];
      of[dt] = __builtin_amdgcn_mfma_f32_16x16x32_bf16(pa0, vb0, of[dt], 0, 0, 0);
      of[dt] = __builtin_amdgcn_mfma_f32_16x16x32_bf16(pa1, vb1, of[dt], 0, 0, 0);
    }
    __builtin_amdgcn_s_setprio(0);
  }
#pragma unroll
  for (int r = 0; r < 4; ++r) {
    const float invl = 1.f / l[r];
#pragma unroll
    for (int dt = 0; dt < 8; ++dt)
      ao[(size_t)(q0 + w * 16 + l4 * 4 + r) * 4096 + h * 128 + dt * 16 + l15] =
          f2bf(of[dt][r] * invl);
  }
}

// ============================================================================
extern "C" void kernel_launch(void* const* d_in, const int* in_sizes, int n_in,
                              void* d_out, int out_size, void* d_ws, size_t ws_size,
                              hipStream_t stream) {
  const float* hidden     = (const float*)d_in[0];
  const int*   positions  = (const int*)d_in[1];
  const float* w_qkv_a    = (const float*)d_in[2];
  const float* q_a_ln_w   = (const float*)d_in[3];
  const float* w_q_b      = (const float*)d_in[4];
  const float* kv_a_ln_w  = (const float*)d_in[5];
  const float* w_kv_b     = (const float*)d_in[6];
  const float* w_o        = (const float*)d_in[7];
  const float* w_idx_qb   = (const float*)d_in[8];
  const float* w_idx_k    = (const float*)d_in[9];
  const float* idx_k_ln_w = (const float*)d_in[10];
  const float* idx_k_ln_b = (const float*)d_in[11];
  const float* w_idx_w    = (const float*)d_in[12];
  float* out = (float*)d_out;

  float* ws = (float*)d_ws;
  size_t off = 0;
  auto take = [&](size_t n) { float* p = ws + off; off += n; return p; };
  short* qcn_bf  = (short*)take((size_t)TT * QLL / 2);
  short* qcn_lo  = (short*)take((size_t)TT * QLL / 2);
  short* kvn_bf  = (short*)take((size_t)TT * KLL / 2);
  short* kpe_bf  = (short*)take((size_t)TT * 32);
  float* wtsb    = take((size_t)TT * INHH);
  float* rope_ct = take((size_t)TT * 32);
  float* rope_st = take((size_t)TT * 32);
  short* kih_g   = (short*)take((size_t)TT * IHDD / 2);
  short* kil_g   = (short*)take((size_t)TT * IHDD / 2);
  short* qhb     = (short*)take((size_t)NHH * TT * 192 / 2);   // bf16 [h][q][192]
  short* kfb     = (short*)take((size_t)NHH * TT * 192 / 2);   // bf16 [h][k][192]
  short* vtb     = (short*)take((size_t)NHH * 128 * TT / 2);   // bf16 [h][d][k]
  short* qih_h   = (short*)take((size_t)INHH * TT * 128 / 2);
  short* qih_l   = (short*)take((size_t)INHH * TT * 128 / 2);
  float* part4   = take((size_t)4 * TT * TT);
  unsigned* maskbuf = (unsigned*)take((size_t)TT * 32);
  short* hid_h   = (short*)take((size_t)TT * HH / 2);
  short* hid_l   = (short*)take((size_t)TT * HH / 2);
  short* wqkva_h = (short*)take((size_t)QLL * HH / 2);
  short* wqkva_l = (short*)take((size_t)QLL * HH / 2);
  short* wtail_t = (short*)take((size_t)640 * HH / 2);
  short* wsk_h   = (short*)take((size_t)256 * HH / 2);
  short* wsk_l   = (short*)take((size_t)256 * HH / 2);
  short* widxqb_h = (short*)take((size_t)HH * QLL / 2);
  short* widxqb_l = (short*)take((size_t)HH * QLL / 2);
  short* wqb_t   = (short*)take((size_t)6144 * QLL / 2);
  short* wkvb_t  = (short*)take((size_t)8192 * KLL / 2);
  short* ao   = (short*)part4;       // alias: part4[0 .. 2.1M floats), dead after topk
  short* wo_t = hid_h;               // alias: hid dead after qkv gemms
  float* skpart = part4;             // alias: 8*1024*256 = 2.1M floats < part4 (not live yet)
  // qkvpart 4x1024x1536 = 6.29M floats = vtb(2.10M)+qih_h(2.10M)+qih_l(2.10M) floats exactly
  float* qkvpart = (float*)vtb;
  // tailpart 4x1024x640 = 2.62M floats < qhb (3.14M floats) — qhb written later by gemm_qb
  float* tailpart = (float*)qhb;
  // w_o split-K partials: 2x1024x4096 = 8.39M floats reusing the qhb..vtb span —
  // qhb/kfb/vtb are dead after attn_mfma; ao lives in part4 and wo_t in hid_h (no overlap).
  float* wopart = (float*)qhb;

  const dim3 blk(256);
  // rope table (only dep: positions)
  rope_tab<<<dim3(TT), 32, 0, stream>>>(positions, rope_ct, rope_st);
  // input/weight splits
  split_cast<<<dim3(TT * HH / 4 / 256), blk, 0, stream>>>(hidden, hid_h, hid_l, TT * HH / 4);
  transpose_split_cast<<<dim3(QLL / 64, HH / 64), blk, 0, stream>>>(w_qkv_a, wqkva_h, wqkva_l, HH, QKVN, 0, QLL);
  transpose_cast_g<<<dim3(640 / 64, HH / 64), blk, 0, stream>>>(w_qkv_a, wtail_t, HH, QKVN, QLL, QKVN - QLL);
  transpose_split_cast<<<dim3(HH / 64, QLL / 64), blk, 0, stream>>>(w_idx_qb, widxqb_h, widxqb_l, QLL, HH, 0, HH);
  transpose_split_cast<<<dim3(2, HH / 64), blk, 0, stream>>>(w_idx_k, wsk_h, wsk_l, HH, 128, 0, 128);
  transpose_split_cast<<<dim3(2, HH / 64), blk, 0, stream>>>(w_idx_w, wsk_h + (size_t)128 * HH,
                                                            wsk_l + (size_t)128 * HH, HH, 32, 0, 32);
  transpose_cast_g<<<dim3(6144 / 64, QLL / 64), blk, 0, stream>>>(w_q_b, wqb_t, QLL, 6144, 0, 6144);
  transpose_cast_g<<<dim3(8192 / 64, KLL / 64), blk, 0, stream>>>(w_kv_b, wkvb_t, KLL, 8192, 0, 8192);
  // skinny projections via bf16x3 MFMA z=8; partials in part4
  gemm3<<<dim3(2, 16, 8), blk, 0, stream>>>(hid_h, hid_l, wsk_h, wsk_l,
                                            skpart, TT, 256, HH, HH / 8);
  ki_prep2<<<dim3(TT), blk, 0, stream>>>(skpart, idx_k_ln_w, idx_k_ln_b, rope_ct, rope_st,
                                         kih_g, kil_g, wtsb);
  // qkv_a q_c: bf16x3 split-K z=4 -> qkvpart (vtb+qih span)
  gemm3<<<dim3(QLL / 128, 16, 4), blk, 0, stream>>>(hid_h, hid_l, wqkva_h, wqkva_l,
                                                    qkvpart, TT, QLL, HH, HH / 4);
  // qkv_a kv/kpe tail: z=4 -> tailpart (qhb span)
  gemm1_splitk<<<dim3(5, 16, 4), blk, 0, stream>>>(hid_h, wtail_t, tailpart, TT, 640, HH, HH / 4);
  // fused epilogue -> qcn hi/lo, kvn, kpe_bf
  qkv_post<<<dim3(TT), blk, 0, stream>>>(qkvpart, tailpart, q_a_ln_w, kv_a_ln_w,
                                         rope_ct, rope_st, qcn_bf, qcn_lo, kvn_bf, kpe_bf);
  // w_o transpose (hid region dead)
  transpose_cast_g<<<dim3(HH / 64, HH / 64), blk, 0, stream>>>(w_o, wo_t, HH, HH, 0, HH);
  // idx_qb: fused bf16x3 GEMM (BK=64, z=1) + rope/repack/split epilogue -> qih directly
  gemm_idx<<<dim3(HH / 128, 16), blk, 0, stream>>>(qcn_bf, qcn_lo, widxqb_h, widxqb_l,
                                                   rope_ct, rope_st, qih_h, qih_l);
  // smooth projections with fused repacks
  gemm_qb<<<dim3(48, 16), blk, 0, stream>>>(qcn_bf, wqb_t, rope_ct, rope_st, qhb);
  gemm_kvb<<<dim3(64, 16), blk, 0, stream>>>(kvn_bf, wkvb_t, kpe_bf, kfb, vtb);
  // indexer logits (triangular + XCD swizzle, 4 planes)
  logits_mfma<<<dim3(136, 4), blk, 0, stream>>>(qih_h, qih_l, kih_g, kil_g, wtsb, part4);
  // top-512 -> bitmask
  topk_mask<<<dim3(TT / 4), blk, 0, stream>>>(part4, maskbuf);
  // masked dense MFMA attention
  attn_mfma<<<dim3(NHH, 16), blk, 0, stream>>>(qhb, kfb, vtb, maskbuf, ao);
  // output projection: split-K z=2 (1024 blocks = 4/CU) + deterministic reduce
  gemm1_splitk<<<dim3(HH / 128, 16, 2), blk, 0, stream>>>(ao, wo_t, wopart, TT, HH,
                                                          NHH * DVV, NHH * DVV / 2);
  reduce_splitk<<<dim3(HH / 256, TT), blk, 0, stream>>>(wopart, out, TT, HH, 2);
}